// Round 8
// baseline (215.663 us; speedup 1.0000x reference)
//
#include <hip/hip_runtime.h>
#include <hip/hip_bf16.h>
#include <cstdint>
#include <cstddef>

#define NNODES 50000
#define NEDGES 800000
#define NIN    512
#define NHID   128
#define NCLS   64

#define SCAN_BLK 512
#define SCAN_NB ((NNODES + SCAN_BLK - 1) / SCAN_BLK)  // 98

typedef __attribute__((ext_vector_type(8))) short bf16x8;
typedef __attribute__((ext_vector_type(4))) float f32x4;

static __device__ __forceinline__ ushort f2bf(float f) {
    uint32_t u = __float_as_uint(f);
    uint32_t r = (u + 0x7fffu + ((u >> 16) & 1u)) >> 16;  // RNE
    return (ushort)r;
}
static __device__ __forceinline__ float bf2f(ushort b) {
    return __uint_as_float(((uint32_t)b) << 16);
}

// ---------------- workspace clear ----------------
__global__ void clear_kernel(int4* __restrict__ p, int n4) {
    int i = blockIdx.x * blockDim.x + threadIdx.x;
    if (i < n4) p[i] = make_int4(0, 0, 0, 0);
}

// ---------------- CSR build ----------------

__global__ void deg_kernel(const int* __restrict__ dst, int* __restrict__ deg) {
    int e = blockIdx.x * blockDim.x + threadIdx.x;
    if (e < NEDGES) atomicAdd(&deg[dst[e]], 1);
}

// phase 1: per-block sums of deg; also compute dinv (fused)
__global__ __launch_bounds__(SCAN_BLK) void scan1_kernel(const int* __restrict__ deg,
                                                         int* __restrict__ blkSum,
                                                         float* __restrict__ dinv) {
    int i = blockIdx.x * SCAN_BLK + threadIdx.x;
    int d = (i < NNODES) ? deg[i] : 0;
    if (i < NNODES) dinv[i] = rsqrtf((float)d + 1.0f);
    int v = d;
#pragma unroll
    for (int off = 32; off; off >>= 1) v += __shfl_xor(v, off, 64);
    __shared__ int ws[SCAN_BLK / 64];
    int w = threadIdx.x >> 6;
    if ((threadIdx.x & 63) == 0) ws[w] = v;
    __syncthreads();
    if (threadIdx.x == 0) {
        int s = 0;
#pragma unroll
        for (int k = 0; k < SCAN_BLK / 64; ++k) s += ws[k];
        blkSum[blockIdx.x] = s;
    }
}

// phase 2: exclusive scan of the 98 block sums (single small block)
__global__ void scan2_kernel(int* __restrict__ blkSum, int* __restrict__ rowptr) {
    __shared__ int sh[128];
    int t = threadIdx.x;
    int v = (t < SCAN_NB) ? blkSum[t] : 0;
    sh[t] = v;
    __syncthreads();
    for (int off = 1; off < 128; off <<= 1) {
        int o = (t >= off) ? sh[t - off] : 0;
        __syncthreads();
        sh[t] += o;
        __syncthreads();
    }
    if (t < SCAN_NB) blkSum[t] = sh[t] - v;  // exclusive
    if (t == 0) rowptr[NNODES] = NEDGES;     // every edge has a dst
}

// phase 3: per-block exclusive scan + block offset -> rowptr
__global__ __launch_bounds__(SCAN_BLK) void scan3_kernel(const int* __restrict__ deg,
                                                         const int* __restrict__ blkOff,
                                                         int* __restrict__ rowptr) {
    int i = blockIdx.x * SCAN_BLK + threadIdx.x;
    int v = (i < NNODES) ? deg[i] : 0;
    int lane = threadIdx.x & 63;
    int w = threadIdx.x >> 6;
    int inc = v;
#pragma unroll
    for (int off = 1; off < 64; off <<= 1) {
        int o = __shfl_up(inc, off, 64);
        if (lane >= off) inc += o;
    }
    __shared__ int ws[SCAN_BLK / 64];
    if (lane == 63) ws[w] = inc;
    __syncthreads();
    int wpre = 0;
    for (int k = 0; k < w; ++k) wpre += ws[k];
    if (i < NNODES) rowptr[i] = inc - v + wpre + blkOff[blockIdx.x];
}

__global__ void scatter_kernel(const int* __restrict__ src, const int* __restrict__ dst,
                               const int* __restrict__ rowptr, int* __restrict__ cursor,
                               const float* __restrict__ dinv, int2* __restrict__ csr) {
    int e = blockIdx.x * blockDim.x + threadIdx.x;
    if (e >= NEDGES) return;
    int d = dst[e];
    int s = src[e];
    int pos = rowptr[d] + atomicAdd(&cursor[d], 1);
    csr[pos] = make_int2(s, __float_as_int(dinv[s]));
}

// ---------------- W pre-pack into MFMA B-fragment order (bf16) ----------------
template <int NOUT, int KS, int CF>
__global__ void pack_kernel(const float* __restrict__ W, ushort* __restrict__ pack) {
    int t = blockIdx.x * blockDim.x + threadIdx.x;
    if (t >= KS * CF * 64 * 8) return;
    int j = t & 7;
    int lane = (t >> 3) & 63;
    int cf = (t >> 9) % CF;
    int ks = t / (CF * 512);
    int k = ks * 32 + (lane >> 4) * 8 + j;
    int c = cf * 16 + (lane & 15);
    pack[t] = f2bf(W[(size_t)k * NOUT + c]);
}

// ---------------- GEMM1: xw1[50000x128](bf16) = x[50000x512](f32) @ packW1 ----------------
// Split-K x4 TLP version: block = 4 waves on the SAME 16 rows; wave w owns K in
// [w*128, w*128+128). 8 independent float4 loads issued up-front per lane (no pipeline
// for the compiler to defeat); latency hidden by 12500 waves of TLP (~24-32 waves/CU).
// Partial C reduced through 24 KB LDS; wave 0 stores. 50000 = 3125*16 -> no row tail.
__global__ __launch_bounds__(256) void gemm1_kernel(const float* __restrict__ A,
                                                    const ushort* __restrict__ packB,
                                                    ushort* __restrict__ C) {
    __shared__ f32x4 red[3][8][64];  // 24 KB
    const int t = threadIdx.x;
    const int lane = t & 63;
    const int w = t >> 6;
    const int rowBase = blockIdx.x * 16;
    const int rl = lane & 15;
    const int kg = lane >> 4;
    const float* ap = A + (size_t)(rowBase + rl) * NIN + w * 128 + kg * 8;

    // all 8 A-loads independent, issued before any use
    float4 xv[8];
#pragma unroll
    for (int ks = 0; ks < 4; ++ks) {
        xv[2 * ks]     = *(const float4*)(ap + ks * 32);
        xv[2 * ks + 1] = *(const float4*)(ap + ks * 32 + 4);
    }

    f32x4 acc[8];
#pragma unroll
    for (int cf = 0; cf < 8; ++cf) acc[cf] = (f32x4)(0.f);

#pragma unroll
    for (int ks = 0; ks < 4; ++ks) {
        float4 x0 = xv[2 * ks], x1 = xv[2 * ks + 1];
        bf16x8 af;
        af[0] = (short)f2bf(x0.x); af[1] = (short)f2bf(x0.y);
        af[2] = (short)f2bf(x0.z); af[3] = (short)f2bf(x0.w);
        af[4] = (short)f2bf(x1.x); af[5] = (short)f2bf(x1.y);
        af[6] = (short)f2bf(x1.z); af[7] = (short)f2bf(x1.w);
        const ushort* bp = packB + ((size_t)((w * 4 + ks) * 8) * 64 + lane) * 8;
#pragma unroll
        for (int cf = 0; cf < 8; ++cf) {
            bf16x8 bfv = *(const bf16x8*)(bp + cf * 512);
            acc[cf] = __builtin_amdgcn_mfma_f32_16x16x32_bf16(af, bfv, acc[cf], 0, 0, 0);
        }
    }

    if (w) {
#pragma unroll
        for (int cf = 0; cf < 8; ++cf) red[w - 1][cf][lane] = acc[cf];
    }
    __syncthreads();
    if (w == 0) {
#pragma unroll
        for (int cf = 0; cf < 8; ++cf)
#pragma unroll
            for (int q = 0; q < 3; ++q) {
                f32x4 v = red[q][cf][lane];
                acc[cf][0] += v[0]; acc[cf][1] += v[1];
                acc[cf][2] += v[2]; acc[cf][3] += v[3];
            }
        // C/D: col = lane&15, row = (lane>>4)*4 + j   [m89-verified]
#pragma unroll
        for (int cf = 0; cf < 8; ++cf)
#pragma unroll
            for (int j = 0; j < 4; ++j)
                C[(size_t)(rowBase + kg * 4 + j) * NHID + cf * 16 + rl] = f2bf(acc[cf][j]);
    }
}

// ---------------- GEMM2: xw2[50000x64](bf16) = h[50000x128](bf16) @ packW2 ----------------
__global__ __launch_bounds__(256) void gemm2_kernel(const ushort* __restrict__ A,
                                                    const ushort* __restrict__ packB,
                                                    ushort* __restrict__ C) {
    int wid = (blockIdx.x * blockDim.x + threadIdx.x) >> 6;
    int lane = threadIdx.x & 63;
    int rowBase = wid * 16;
    if (rowBase >= NNODES) return;
    int rl = lane & 15;
    int kg = lane >> 4;
    const ushort* ap = A + (size_t)(rowBase + rl) * NHID + kg * 8;

    f32x4 acc[4];
#pragma unroll
    for (int cf = 0; cf < 4; ++cf) acc[cf] = (f32x4)(0.f);

#pragma unroll
    for (int ks = 0; ks < 4; ++ks) {
        bf16x8 af = *(const bf16x8*)(ap + ks * 32);
        const ushort* bp = packB + ((size_t)(ks * 4) * 64 + lane) * 8;
#pragma unroll
        for (int cf = 0; cf < 4; ++cf) {
            bf16x8 bf = *(const bf16x8*)(bp + (size_t)cf * 512);
            acc[cf] = __builtin_amdgcn_mfma_f32_16x16x32_bf16(af, bf, acc[cf], 0, 0, 0);
        }
    }
#pragma unroll
    for (int cf = 0; cf < 4; ++cf)
#pragma unroll
        for (int j = 0; j < 4; ++j)
            C[(size_t)(rowBase + kg * 4 + j) * NCLS + cf * 16 + rl] = f2bf(acc[cf][j]);
}

// ---------------- agg1: h = relu(agg(xw1) + b1), one wave per node, bf16 in/out ----------------
__global__ __launch_bounds__(256) void agg1_kernel(const ushort* __restrict__ xw,
                                                   const int* __restrict__ rowptr,
                                                   const int2* __restrict__ csr,
                                                   const float* __restrict__ dinv,
                                                   const float* __restrict__ b1,
                                                   ushort* __restrict__ h) {
    int wid = (blockIdx.x * blockDim.x + threadIdx.x) >> 6;
    int lane = threadIdx.x & 63;
    if (wid >= NNODES) return;
    int beg = rowptr[wid], end = rowptr[wid + 1];
    float a0 = 0.f, a1 = 0.f;
    int j = beg;
    for (; j + 8 <= end; j += 8) {
        int2 e[8];
#pragma unroll
        for (int q = 0; q < 8; ++q) e[q] = csr[j + q];
        uint v[8];
#pragma unroll
        for (int q = 0; q < 8; ++q) v[q] = *(const uint*)&xw[(size_t)e[q].x * NHID + lane * 2];
#pragma unroll
        for (int q = 0; q < 8; ++q) {
            float wq = __int_as_float(e[q].y);
            a0 += wq * __uint_as_float(v[q] << 16);
            a1 += wq * __uint_as_float(v[q] & 0xffff0000u);
        }
    }
    for (; j < end; ++j) {
        int2 e = csr[j];
        float w = __int_as_float(e.y);
        uint v = *(const uint*)&xw[(size_t)e.x * NHID + lane * 2];
        a0 += w * __uint_as_float(v << 16);
        a1 += w * __uint_as_float(v & 0xffff0000u);
    }
    float di = dinv[wid];
    float sl = di * di;
    uint xv = *(const uint*)&xw[(size_t)wid * NHID + lane * 2];
    float2 bv = *(const float2*)&b1[lane * 2];
    float r0 = di * a0 + sl * __uint_as_float(xv << 16) + bv.x;
    float r1 = di * a1 + sl * __uint_as_float(xv & 0xffff0000u) + bv.y;
    uint o = (uint)f2bf(fmaxf(r0, 0.f)) | ((uint)f2bf(fmaxf(r1, 0.f)) << 16);
    *(uint*)&h[(size_t)wid * NHID + lane * 2] = o;
}

// ---------------- agg2 + bias + log_softmax, one wave per node, bf16 in, f32 out ----------------
__global__ __launch_bounds__(256) void agg2_kernel(const ushort* __restrict__ xw,
                                                   const int* __restrict__ rowptr,
                                                   const int2* __restrict__ csr,
                                                   const float* __restrict__ dinv,
                                                   const float* __restrict__ b2,
                                                   float* __restrict__ out) {
    int wid = (blockIdx.x * blockDim.x + threadIdx.x) >> 6;
    int lane = threadIdx.x & 63;
    if (wid >= NNODES) return;
    int beg = rowptr[wid], end = rowptr[wid + 1];
    float a = 0.f;
    int j = beg;
    for (; j + 8 <= end; j += 8) {
        int2 e[8];
#pragma unroll
        for (int q = 0; q < 8; ++q) e[q] = csr[j + q];
        float v[8];
#pragma unroll
        for (int q = 0; q < 8; ++q) v[q] = bf2f(xw[(size_t)e[q].x * NCLS + lane]);
#pragma unroll
        for (int q = 0; q < 8; ++q) a += __int_as_float(e[q].y) * v[q];
    }
    for (; j < end; ++j) {
        int2 e = csr[j];
        a += __int_as_float(e.y) * bf2f(xw[(size_t)e.x * NCLS + lane]);
    }
    float di = dinv[wid];
    float o = di * a + di * di * bf2f(xw[(size_t)wid * NCLS + lane]) + b2[lane];
    float m = o;
#pragma unroll
    for (int off = 32; off; off >>= 1) m = fmaxf(m, __shfl_xor(m, off, 64));
    float ex = __expf(o - m);
    float ssum = ex;
#pragma unroll
    for (int off = 32; off; off >>= 1) ssum += __shfl_xor(ssum, off, 64);
    out[(size_t)wid * NCLS + lane] = (o - m) - __logf(ssum);
}

// ---------------- launch ----------------

extern "C" void kernel_launch(void* const* d_in, const int* in_sizes, int n_in,
                              void* d_out, int out_size, void* d_ws, size_t ws_size,
                              hipStream_t stream) {
    const float* x  = (const float*)d_in[0];
    const int*   ei = (const int*)d_in[1];
    const int*   src = ei;
    const int*   dst = ei + NEDGES;
    const float* W1 = (const float*)d_in[2];
    const float* b1 = (const float*)d_in[3];
    const float* W2 = (const float*)d_in[4];
    const float* b2 = (const float*)d_in[5];
    float* out = (float*)d_out;

    char* w = (char*)d_ws;
    auto alloc = [&](size_t bytes) {
        char* p = w;
        w += (bytes + 255) & ~(size_t)255;
        return p;
    };
    int*    deg    = (int*)alloc((size_t)2 * NNODES * 4);  // deg + cursor (one clear)
    int*    cursor = deg + NNODES;
    int*    rowptr = (int*)alloc((NNODES + 1) * 4);
    int*    blkSum = (int*)alloc(SCAN_NB * 4);
    int2*   csr    = (int2*)alloc((size_t)NEDGES * 8);
    float*  dinv   = (float*)alloc(NNODES * 4);
    ushort* pack1  = (ushort*)alloc((size_t)16 * 8 * 64 * 8 * 2);
    ushort* pack2  = (ushort*)alloc((size_t)4 * 4 * 64 * 8 * 2);
    ushort* xw1    = (ushort*)alloc((size_t)NNODES * NHID * 2);
    ushort* h      = (ushort*)alloc((size_t)NNODES * NHID * 2);
    ushort* xw2    = (ushort*)alloc((size_t)NNODES * NCLS * 2);

    const int n4 = (2 * NNODES + 3) / 4;  // deg+cursor as int4
    clear_kernel<<<(n4 + 255) / 256, 256, 0, stream>>>((int4*)deg, n4);

    deg_kernel<<<(NEDGES + 255) / 256, 256, 0, stream>>>(dst, deg);
    scan1_kernel<<<SCAN_NB, SCAN_BLK, 0, stream>>>(deg, blkSum, dinv);
    scan2_kernel<<<1, 128, 0, stream>>>(blkSum, rowptr);
    scan3_kernel<<<SCAN_NB, SCAN_BLK, 0, stream>>>(deg, blkSum, rowptr);
    scatter_kernel<<<(NEDGES + 255) / 256, 256, 0, stream>>>(src, dst, rowptr, cursor, dinv, csr);

    pack_kernel<NHID, 16, 8><<<(16 * 8 * 64 * 8 + 255) / 256, 256, 0, stream>>>(W1, pack1);
    pack_kernel<NCLS, 4, 4><<<(4 * 4 * 64 * 8 + 255) / 256, 256, 0, stream>>>(W2, pack2);

    // layer 1 (split-K x4: 3125 blocks x 256 threads)
    gemm1_kernel<<<NNODES / 16, 256, 0, stream>>>(x, pack1, xw1);
    agg1_kernel<<<(NNODES * 64 + 255) / 256, 256, 0, stream>>>(xw1, rowptr, csr, dinv, b1, h);

    // layer 2 (+ fused bias + log_softmax)
    gemm2_kernel<<<(NNODES / 16 + 3) / 4, 256, 0, stream>>>(h, pack2, xw2);
    agg2_kernel<<<(NNODES * 64 + 255) / 256, 256, 0, stream>>>(xw2, rowptr, csr, dinv, b2, out);
}

// Round 9
// 212.961 us; speedup vs baseline: 1.0127x; 1.0127x over previous
//
#include <hip/hip_runtime.h>
#include <hip/hip_bf16.h>
#include <cstdint>
#include <cstddef>

#define NNODES 50000
#define NEDGES 800000
#define NIN    512
#define NHID   128
#define NCLS   64

#define SCAN_BLK 512
#define SCAN_NB ((NNODES + SCAN_BLK - 1) / SCAN_BLK)  // 98

typedef __attribute__((ext_vector_type(8))) short bf16x8;
typedef __attribute__((ext_vector_type(4))) float f32x4;

static __device__ __forceinline__ ushort f2bf(float f) {
    uint32_t u = __float_as_uint(f);
    uint32_t r = (u + 0x7fffu + ((u >> 16) & 1u)) >> 16;  // RNE
    return (ushort)r;
}
static __device__ __forceinline__ float bf2f(ushort b) {
    return __uint_as_float(((uint32_t)b) << 16);
}

// ---------------- workspace clear ----------------
__global__ void clear_kernel(int4* __restrict__ p, int n4) {
    int i = blockIdx.x * blockDim.x + threadIdx.x;
    if (i < n4) p[i] = make_int4(0, 0, 0, 0);
}

// ---------------- CSR build ----------------

__global__ void deg_kernel(const int* __restrict__ dst, int* __restrict__ deg) {
    int e = blockIdx.x * blockDim.x + threadIdx.x;
    if (e < NEDGES) atomicAdd(&deg[dst[e]], 1);
}

// phase 1: per-block sums of deg; also compute dinv (fused)
__global__ __launch_bounds__(SCAN_BLK) void scan1_kernel(const int* __restrict__ deg,
                                                         int* __restrict__ blkSum,
                                                         float* __restrict__ dinv) {
    int i = blockIdx.x * SCAN_BLK + threadIdx.x;
    int d = (i < NNODES) ? deg[i] : 0;
    if (i < NNODES) dinv[i] = rsqrtf((float)d + 1.0f);
    int v = d;
#pragma unroll
    for (int off = 32; off; off >>= 1) v += __shfl_xor(v, off, 64);
    __shared__ int ws[SCAN_BLK / 64];
    int w = threadIdx.x >> 6;
    if ((threadIdx.x & 63) == 0) ws[w] = v;
    __syncthreads();
    if (threadIdx.x == 0) {
        int s = 0;
#pragma unroll
        for (int k = 0; k < SCAN_BLK / 64; ++k) s += ws[k];
        blkSum[blockIdx.x] = s;
    }
}

// phase 2: exclusive scan of the 98 block sums (single small block)
__global__ void scan2_kernel(int* __restrict__ blkSum, int* __restrict__ rowptr) {
    __shared__ int sh[128];
    int t = threadIdx.x;
    int v = (t < SCAN_NB) ? blkSum[t] : 0;
    sh[t] = v;
    __syncthreads();
    for (int off = 1; off < 128; off <<= 1) {
        int o = (t >= off) ? sh[t - off] : 0;
        __syncthreads();
        sh[t] += o;
        __syncthreads();
    }
    if (t < SCAN_NB) blkSum[t] = sh[t] - v;  // exclusive
    if (t == 0) rowptr[NNODES] = NEDGES;     // every edge has a dst
}

// phase 3: per-block exclusive scan + block offset -> rowptr
__global__ __launch_bounds__(SCAN_BLK) void scan3_kernel(const int* __restrict__ deg,
                                                         const int* __restrict__ blkOff,
                                                         int* __restrict__ rowptr) {
    int i = blockIdx.x * SCAN_BLK + threadIdx.x;
    int v = (i < NNODES) ? deg[i] : 0;
    int lane = threadIdx.x & 63;
    int w = threadIdx.x >> 6;
    int inc = v;
#pragma unroll
    for (int off = 1; off < 64; off <<= 1) {
        int o = __shfl_up(inc, off, 64);
        if (lane >= off) inc += o;
    }
    __shared__ int ws[SCAN_BLK / 64];
    if (lane == 63) ws[w] = inc;
    __syncthreads();
    int wpre = 0;
    for (int k = 0; k < w; ++k) wpre += ws[k];
    if (i < NNODES) rowptr[i] = inc - v + wpre + blkOff[blockIdx.x];
}

__global__ void scatter_kernel(const int* __restrict__ src, const int* __restrict__ dst,
                               const int* __restrict__ rowptr, int* __restrict__ cursor,
                               const float* __restrict__ dinv, int2* __restrict__ csr) {
    int e = blockIdx.x * blockDim.x + threadIdx.x;
    if (e >= NEDGES) return;
    int d = dst[e];
    int s = src[e];
    int pos = rowptr[d] + atomicAdd(&cursor[d], 1);
    csr[pos] = make_int2(s, __float_as_int(dinv[s]));
}

// ---------------- W pre-pack into MFMA B-fragment order (bf16) ----------------
template <int NOUT, int KS, int CF>
__global__ void pack_kernel(const float* __restrict__ W, ushort* __restrict__ pack) {
    int t = blockIdx.x * blockDim.x + threadIdx.x;
    if (t >= KS * CF * 64 * 8) return;
    int j = t & 7;
    int lane = (t >> 3) & 63;
    int cf = (t >> 9) % CF;
    int ks = t / (CF * 512);
    int k = ks * 32 + (lane >> 4) * 8 + j;
    int c = cf * 16 + (lane & 15);
    pack[t] = f2bf(W[(size_t)k * NOUT + c]);
}

// ---------------- GEMM1: xw1[50000x128](bf16) = x[50000x512](f32) @ packW1 ----------------
// One wave per block (64 threads, 3125 blocks -> ~12 blocks/CU TLP). 3-buffer LDS rotation
// (12 KB) fed by global_load_lds; NO barriers (single wave) -> nothing drains the pipeline.
// Counted s_waitcnt vmcnt(8/4/0): two chunks always in flight (T3+T4). sched_barrier(0)
// fences ds_read hoisting past the wait (rule #18); lgkmcnt(0) fences LDS buffer reuse.
// XOR swizzle both sides (rule #21): stored colblk = logical ^ (row&7); linear LDS dest,
// pre-swizzled global source, swizzled ds_read -> conflict-free b128.
__global__ __launch_bounds__(64) void gemm1_kernel(const float* __restrict__ A,
                                                   const ushort* __restrict__ packB,
                                                   ushort* __restrict__ C) {
    __shared__ float lds[3][16 * 64];  // 3 x 4 KB
    const int lane = threadIdx.x;
    const int rowBase = blockIdx.x * 16;   // 50000 = 3125*16, no tail
    const int rl = lane & 15;
    const int kg = lane >> 4;
    const int srow = lane >> 4;   // staging: sub-row within 4-row group
    const int scol = lane & 15;   // staging: stored 16B col-block
    const char* Abase = (const char*)A + (size_t)rowBase * (NIN * 4);

    f32x4 acc[8];
#pragma unroll
    for (int cf = 0; cf < 8; ++cf) acc[cf] = (f32x4)(0.f);

    auto stage = [&](int buf, int chunk) {
#pragma unroll
        for (int r = 0; r < 4; ++r) {
            const int row = r * 4 + srow;
            const char* src = Abase + (size_t)row * (NIN * 4) + chunk * 256
                              + ((scol ^ (row & 7)) << 4);   // inverse-swizzled source
            char* dst = (char*)&lds[buf][0] + r * 1024 + lane * 16;  // linear dest
            __builtin_amdgcn_global_load_lds((const uint32_t*)src, (uint32_t*)dst, 16, 0, 0);
        }
    };

    stage(0, 0);
    stage(1, 1);

#define G1_CHUNK(c, VMSTR)                                                              \
    {                                                                                   \
        if ((c) + 2 < 8) {                                                              \
            asm volatile("s_waitcnt lgkmcnt(0)" ::: "memory"); /* buf reuse fence */    \
            stage(((c) + 2) % 3, (c) + 2);                                              \
        }                                                                               \
        asm volatile("s_waitcnt " VMSTR ::: "memory");                                  \
        __builtin_amdgcn_sched_barrier(0);                                              \
        const char* lrow = (const char*)&lds[(c) % 3][0] + rl * 256;                    \
        _Pragma("unroll")                                                               \
        for (int ks = 0; ks < 2; ++ks) {                                                \
            const int blk = kg * 2 + ks * 8;                                            \
            float4 x0 = *(const float4*)(lrow + (((blk) ^ (rl & 7)) << 4));             \
            float4 x1 = *(const float4*)(lrow + (((blk + 1) ^ (rl & 7)) << 4));         \
            bf16x8 af;                                                                  \
            af[0] = (short)f2bf(x0.x); af[1] = (short)f2bf(x0.y);                       \
            af[2] = (short)f2bf(x0.z); af[3] = (short)f2bf(x0.w);                       \
            af[4] = (short)f2bf(x1.x); af[5] = (short)f2bf(x1.y);                       \
            af[6] = (short)f2bf(x1.z); af[7] = (short)f2bf(x1.w);                       \
            const ushort* bpp = packB + ((size_t)(((c) * 2 + ks) * 8) * 64 + lane) * 8; \
            _Pragma("unroll")                                                           \
            for (int cf = 0; cf < 8; ++cf) {                                            \
                bf16x8 bfv = *(const bf16x8*)(bpp + cf * 512);                          \
                acc[cf] = __builtin_amdgcn_mfma_f32_16x16x32_bf16(af, bfv, acc[cf], 0, 0, 0); \
            }                                                                           \
        }                                                                               \
    }

    G1_CHUNK(0, "vmcnt(8)")
    G1_CHUNK(1, "vmcnt(8)")
    G1_CHUNK(2, "vmcnt(8)")
    G1_CHUNK(3, "vmcnt(8)")
    G1_CHUNK(4, "vmcnt(8)")
    G1_CHUNK(5, "vmcnt(8)")
    G1_CHUNK(6, "vmcnt(4)")
    G1_CHUNK(7, "vmcnt(0)")
#undef G1_CHUNK

    // C/D: col = lane&15, row = (lane>>4)*4 + j   [m89-verified]
#pragma unroll
    for (int cf = 0; cf < 8; ++cf)
#pragma unroll
        for (int j = 0; j < 4; ++j)
            C[(size_t)(rowBase + kg * 4 + j) * NHID + cf * 16 + rl] = f2bf(acc[cf][j]);
}

// ---------------- GEMM2: xw2[50000x64](bf16) = h[50000x128](bf16) @ packW2 ----------------
__global__ __launch_bounds__(256) void gemm2_kernel(const ushort* __restrict__ A,
                                                    const ushort* __restrict__ packB,
                                                    ushort* __restrict__ C) {
    int wid = (blockIdx.x * blockDim.x + threadIdx.x) >> 6;
    int lane = threadIdx.x & 63;
    int rowBase = wid * 16;
    if (rowBase >= NNODES) return;
    int rl = lane & 15;
    int kg = lane >> 4;
    const ushort* ap = A + (size_t)(rowBase + rl) * NHID + kg * 8;

    f32x4 acc[4];
#pragma unroll
    for (int cf = 0; cf < 4; ++cf) acc[cf] = (f32x4)(0.f);

#pragma unroll
    for (int ks = 0; ks < 4; ++ks) {
        bf16x8 af = *(const bf16x8*)(ap + ks * 32);
        const ushort* bp = packB + ((size_t)(ks * 4) * 64 + lane) * 8;
#pragma unroll
        for (int cf = 0; cf < 4; ++cf) {
            bf16x8 bf = *(const bf16x8*)(bp + (size_t)cf * 512);
            acc[cf] = __builtin_amdgcn_mfma_f32_16x16x32_bf16(af, bf, acc[cf], 0, 0, 0);
        }
    }
#pragma unroll
    for (int cf = 0; cf < 4; ++cf)
#pragma unroll
        for (int j = 0; j < 4; ++j)
            C[(size_t)(rowBase + kg * 4 + j) * NCLS + cf * 16 + rl] = f2bf(acc[cf][j]);
}

// ---------------- agg1: h = relu(agg(xw1) + b1), one wave per node, bf16 in/out ----------------
__global__ __launch_bounds__(256) void agg1_kernel(const ushort* __restrict__ xw,
                                                   const int* __restrict__ rowptr,
                                                   const int2* __restrict__ csr,
                                                   const float* __restrict__ dinv,
                                                   const float* __restrict__ b1,
                                                   ushort* __restrict__ h) {
    int wid = (blockIdx.x * blockDim.x + threadIdx.x) >> 6;
    int lane = threadIdx.x & 63;
    if (wid >= NNODES) return;
    int beg = rowptr[wid], end = rowptr[wid + 1];
    float a0 = 0.f, a1 = 0.f;
    int j = beg;
    for (; j + 8 <= end; j += 8) {
        int2 e[8];
#pragma unroll
        for (int q = 0; q < 8; ++q) e[q] = csr[j + q];
        uint v[8];
#pragma unroll
        for (int q = 0; q < 8; ++q) v[q] = *(const uint*)&xw[(size_t)e[q].x * NHID + lane * 2];
#pragma unroll
        for (int q = 0; q < 8; ++q) {
            float wq = __int_as_float(e[q].y);
            a0 += wq * __uint_as_float(v[q] << 16);
            a1 += wq * __uint_as_float(v[q] & 0xffff0000u);
        }
    }
    for (; j < end; ++j) {
        int2 e = csr[j];
        float w = __int_as_float(e.y);
        uint v = *(const uint*)&xw[(size_t)e.x * NHID + lane * 2];
        a0 += w * __uint_as_float(v << 16);
        a1 += w * __uint_as_float(v & 0xffff0000u);
    }
    float di = dinv[wid];
    float sl = di * di;
    uint xv = *(const uint*)&xw[(size_t)wid * NHID + lane * 2];
    float2 bv = *(const float2*)&b1[lane * 2];
    float r0 = di * a0 + sl * __uint_as_float(xv << 16) + bv.x;
    float r1 = di * a1 + sl * __uint_as_float(xv & 0xffff0000u) + bv.y;
    uint o = (uint)f2bf(fmaxf(r0, 0.f)) | ((uint)f2bf(fmaxf(r1, 0.f)) << 16);
    *(uint*)&h[(size_t)wid * NHID + lane * 2] = o;
}

// ---------------- agg2 + bias + log_softmax, one wave per node, bf16 in, f32 out ----------------
__global__ __launch_bounds__(256) void agg2_kernel(const ushort* __restrict__ xw,
                                                   const int* __restrict__ rowptr,
                                                   const int2* __restrict__ csr,
                                                   const float* __restrict__ dinv,
                                                   const float* __restrict__ b2,
                                                   float* __restrict__ out) {
    int wid = (blockIdx.x * blockDim.x + threadIdx.x) >> 6;
    int lane = threadIdx.x & 63;
    if (wid >= NNODES) return;
    int beg = rowptr[wid], end = rowptr[wid + 1];
    float a = 0.f;
    int j = beg;
    for (; j + 8 <= end; j += 8) {
        int2 e[8];
#pragma unroll
        for (int q = 0; q < 8; ++q) e[q] = csr[j + q];
        float v[8];
#pragma unroll
        for (int q = 0; q < 8; ++q) v[q] = bf2f(xw[(size_t)e[q].x * NCLS + lane]);
#pragma unroll
        for (int q = 0; q < 8; ++q) a += __int_as_float(e[q].y) * v[q];
    }
    for (; j < end; ++j) {
        int2 e = csr[j];
        a += __int_as_float(e.y) * bf2f(xw[(size_t)e.x * NCLS + lane]);
    }
    float di = dinv[wid];
    float o = di * a + di * di * bf2f(xw[(size_t)wid * NCLS + lane]) + b2[lane];
    float m = o;
#pragma unroll
    for (int off = 32; off; off >>= 1) m = fmaxf(m, __shfl_xor(m, off, 64));
    float ex = __expf(o - m);
    float ssum = ex;
#pragma unroll
    for (int off = 32; off; off >>= 1) ssum += __shfl_xor(ssum, off, 64);
    out[(size_t)wid * NCLS + lane] = (o - m) - __logf(ssum);
}

// ---------------- launch ----------------

extern "C" void kernel_launch(void* const* d_in, const int* in_sizes, int n_in,
                              void* d_out, int out_size, void* d_ws, size_t ws_size,
                              hipStream_t stream) {
    const float* x  = (const float*)d_in[0];
    const int*   ei = (const int*)d_in[1];
    const int*   src = ei;
    const int*   dst = ei + NEDGES;
    const float* W1 = (const float*)d_in[2];
    const float* b1 = (const float*)d_in[3];
    const float* W2 = (const float*)d_in[4];
    const float* b2 = (const float*)d_in[5];
    float* out = (float*)d_out;

    char* w = (char*)d_ws;
    auto alloc = [&](size_t bytes) {
        char* p = w;
        w += (bytes + 255) & ~(size_t)255;
        return p;
    };
    int*    deg    = (int*)alloc((size_t)2 * NNODES * 4);  // deg + cursor (one clear)
    int*    cursor = deg + NNODES;
    int*    rowptr = (int*)alloc((NNODES + 1) * 4);
    int*    blkSum = (int*)alloc(SCAN_NB * 4);
    int2*   csr    = (int2*)alloc((size_t)NEDGES * 8);
    float*  dinv   = (float*)alloc(NNODES * 4);
    ushort* pack1  = (ushort*)alloc((size_t)16 * 8 * 64 * 8 * 2);
    ushort* pack2  = (ushort*)alloc((size_t)4 * 4 * 64 * 8 * 2);
    ushort* xw1    = (ushort*)alloc((size_t)NNODES * NHID * 2);
    ushort* h      = (ushort*)alloc((size_t)NNODES * NHID * 2);
    ushort* xw2    = (ushort*)alloc((size_t)NNODES * NCLS * 2);

    const int n4 = (2 * NNODES + 3) / 4;  // deg+cursor as int4
    clear_kernel<<<(n4 + 255) / 256, 256, 0, stream>>>((int4*)deg, n4);

    deg_kernel<<<(NEDGES + 255) / 256, 256, 0, stream>>>(dst, deg);
    scan1_kernel<<<SCAN_NB, SCAN_BLK, 0, stream>>>(deg, blkSum, dinv);
    scan2_kernel<<<1, 128, 0, stream>>>(blkSum, rowptr);
    scan3_kernel<<<SCAN_NB, SCAN_BLK, 0, stream>>>(deg, blkSum, rowptr);
    scatter_kernel<<<(NEDGES + 255) / 256, 256, 0, stream>>>(src, dst, rowptr, cursor, dinv, csr);

    pack_kernel<NHID, 16, 8><<<(16 * 8 * 64 * 8 + 255) / 256, 256, 0, stream>>>(W1, pack1);
    pack_kernel<NCLS, 4, 4><<<(4 * 4 * 64 * 8 + 255) / 256, 256, 0, stream>>>(W2, pack2);

    // layer 1 (1 wave/block, counted-vmcnt LDS pipeline)
    gemm1_kernel<<<NNODES / 16, 64, 0, stream>>>(x, pack1, xw1);
    agg1_kernel<<<(NNODES * 64 + 255) / 256, 256, 0, stream>>>(xw1, rowptr, csr, dinv, b1, h);

    // layer 2 (+ fused bias + log_softmax)
    gemm2_kernel<<<(NNODES / 16 + 3) / 4, 256, 0, stream>>>(h, pack2, xw2);
    agg2_kernel<<<(NNODES * 64 + 255) / 256, 256, 0, stream>>>(xw2, rowptr, csr, dinv, b2, out);
}

// Round 10
// 211.090 us; speedup vs baseline: 1.0217x; 1.0089x over previous
//
#include <hip/hip_runtime.h>
#include <hip/hip_bf16.h>
#include <cstdint>
#include <cstddef>

#define NNODES 50000
#define NEDGES 800000
#define NIN    512
#define NHID   128
#define NCLS   64

#define SCAN_BLK 512
#define SCAN_NB ((NNODES + SCAN_BLK - 1) / SCAN_BLK)  // 98

typedef __attribute__((ext_vector_type(8))) short bf16x8;
typedef __attribute__((ext_vector_type(4))) float f32x4;

static __device__ __forceinline__ ushort f2bf(float f) {
    uint32_t u = __float_as_uint(f);
    uint32_t r = (u + 0x7fffu + ((u >> 16) & 1u)) >> 16;  // RNE
    return (ushort)r;
}
static __device__ __forceinline__ float bf2f(ushort b) {
    return __uint_as_float(((uint32_t)b) << 16);
}

// generic (LDS-backed) pointer -> 32-bit LDS byte offset for inline-asm ds_read
static __device__ __forceinline__ unsigned ldsAddr(const void* p) {
    return (unsigned)(size_t)(__attribute__((address_space(3))) const void*)p;
}

// ---------------- workspace clear ----------------
__global__ void clear_kernel(int4* __restrict__ p, int n4) {
    int i = blockIdx.x * blockDim.x + threadIdx.x;
    if (i < n4) p[i] = make_int4(0, 0, 0, 0);
}

// ---------------- CSR build ----------------

__global__ void deg_kernel(const int* __restrict__ dst, int* __restrict__ deg) {
    int e = blockIdx.x * blockDim.x + threadIdx.x;
    if (e < NEDGES) atomicAdd(&deg[dst[e]], 1);
}

// phase 1: per-block sums of deg; also compute dinv (fused)
__global__ __launch_bounds__(SCAN_BLK) void scan1_kernel(const int* __restrict__ deg,
                                                         int* __restrict__ blkSum,
                                                         float* __restrict__ dinv) {
    int i = blockIdx.x * SCAN_BLK + threadIdx.x;
    int d = (i < NNODES) ? deg[i] : 0;
    if (i < NNODES) dinv[i] = rsqrtf((float)d + 1.0f);
    int v = d;
#pragma unroll
    for (int off = 32; off; off >>= 1) v += __shfl_xor(v, off, 64);
    __shared__ int ws[SCAN_BLK / 64];
    int w = threadIdx.x >> 6;
    if ((threadIdx.x & 63) == 0) ws[w] = v;
    __syncthreads();
    if (threadIdx.x == 0) {
        int s = 0;
#pragma unroll
        for (int k = 0; k < SCAN_BLK / 64; ++k) s += ws[k];
        blkSum[blockIdx.x] = s;
    }
}

// phase 2: exclusive scan of the 98 block sums (single small block)
__global__ void scan2_kernel(int* __restrict__ blkSum, int* __restrict__ rowptr) {
    __shared__ int sh[128];
    int t = threadIdx.x;
    int v = (t < SCAN_NB) ? blkSum[t] : 0;
    sh[t] = v;
    __syncthreads();
    for (int off = 1; off < 128; off <<= 1) {
        int o = (t >= off) ? sh[t - off] : 0;
        __syncthreads();
        sh[t] += o;
        __syncthreads();
    }
    if (t < SCAN_NB) blkSum[t] = sh[t] - v;  // exclusive
    if (t == 0) rowptr[NNODES] = NEDGES;     // every edge has a dst
}

// phase 3: per-block exclusive scan + block offset -> rowptr
__global__ __launch_bounds__(SCAN_BLK) void scan3_kernel(const int* __restrict__ deg,
                                                         const int* __restrict__ blkOff,
                                                         int* __restrict__ rowptr) {
    int i = blockIdx.x * SCAN_BLK + threadIdx.x;
    int v = (i < NNODES) ? deg[i] : 0;
    int lane = threadIdx.x & 63;
    int w = threadIdx.x >> 6;
    int inc = v;
#pragma unroll
    for (int off = 1; off < 64; off <<= 1) {
        int o = __shfl_up(inc, off, 64);
        if (lane >= off) inc += o;
    }
    __shared__ int ws[SCAN_BLK / 64];
    if (lane == 63) ws[w] = inc;
    __syncthreads();
    int wpre = 0;
    for (int k = 0; k < w; ++k) wpre += ws[k];
    if (i < NNODES) rowptr[i] = inc - v + wpre + blkOff[blockIdx.x];
}

__global__ void scatter_kernel(const int* __restrict__ src, const int* __restrict__ dst,
                               const int* __restrict__ rowptr, int* __restrict__ cursor,
                               const float* __restrict__ dinv, int2* __restrict__ csr) {
    int e = blockIdx.x * blockDim.x + threadIdx.x;
    if (e >= NEDGES) return;
    int d = dst[e];
    int s = src[e];
    int pos = rowptr[d] + atomicAdd(&cursor[d], 1);
    csr[pos] = make_int2(s, __float_as_int(dinv[s]));
}

// ---------------- W pre-pack into MFMA B-fragment order (bf16) ----------------
template <int NOUT, int KS, int CF>
__global__ void pack_kernel(const float* __restrict__ W, ushort* __restrict__ pack) {
    int t = blockIdx.x * blockDim.x + threadIdx.x;
    if (t >= KS * CF * 64 * 8) return;
    int j = t & 7;
    int lane = (t >> 3) & 63;
    int cf = (t >> 9) % CF;
    int ks = t / (CF * 512);
    int k = ks * 32 + (lane >> 4) * 8 + j;
    int c = cf * 16 + (lane & 15);
    pack[t] = f2bf(W[(size_t)k * NOUT + c]);
}

// ---------------- GEMM1: xw1[50000x128](bf16) = x[50000x512](f32) @ packW1 ----------------
// Single-wave blocks, 3-buffer LDS rotation fed by global_load_lds, counted vmcnt.
// KEY FIX vs prior rounds: the LDS reads are INLINE-ASM ds_read_b128 -> the compiler's
// memory legalizer cannot see the gload_lds->ds_read dependency and does NOT insert its
// own conservative s_waitcnt vmcnt(0) per chunk (which was fully draining the pipeline).
// Manual waits, derived with B-load pollution + in-order vmcnt retirement (m135):
// need stage(c) retired => allow newest {B(c-2), stage(c+1), B(c-1), stage(c+2)} in flight.
// Per rule #18: lgkmcnt(0) + sched_barrier(0) after asm ds_reads, before consumption.
__global__ __launch_bounds__(64) void gemm1_kernel(const float* __restrict__ A,
                                                   const ushort* __restrict__ packB,
                                                   ushort* __restrict__ C) {
    __shared__ float lds[3][16 * 64];  // 3 x 4 KB
    const int lane = threadIdx.x;
    const int rowBase = blockIdx.x * 16;   // 50000 = 3125*16, no tail
    const int rl = lane & 15;
    const int kg = lane >> 4;
    const int srow = lane >> 4;   // staging: sub-row within 4-row group
    const int scol = lane & 15;   // staging: stored 16B col-block
    const int xsw = rl & 7;       // compute-side swizzle
    const char* Abase = (const char*)A + (size_t)rowBase * (NIN * 4);

    f32x4 acc[8];
#pragma unroll
    for (int cf = 0; cf < 8; ++cf) acc[cf] = (f32x4)(0.f);

    auto stage = [&](int buf, int chunk) {
#pragma unroll
        for (int r = 0; r < 4; ++r) {
            const int row = r * 4 + srow;
            const char* src = Abase + (size_t)row * (NIN * 4) + chunk * 256
                              + ((scol ^ (row & 7)) << 4);   // inverse-swizzled source
            char* dst = (char*)&lds[buf][0] + r * 1024 + lane * 16;  // linear dest
            __builtin_amdgcn_global_load_lds((const uint32_t*)src, (uint32_t*)dst, 16, 0, 0);
        }
    };

    stage(0, 0);
    stage(1, 1);

#define G1_CHUNK(c, VMSTR)                                                              \
    {                                                                                   \
        if ((c) + 2 < 8) stage(((c) + 2) % 3, (c) + 2);                                 \
        asm volatile("s_waitcnt vmcnt(" VMSTR ")" ::: "memory");                        \
        __builtin_amdgcn_sched_barrier(0);                                              \
        const unsigned lbase = ldsAddr(&lds[(c) % 3][0]) + (unsigned)(rl * 256);        \
        const unsigned a0 = lbase + (unsigned)((((kg * 2 + 0) ^ xsw)) << 4);            \
        const unsigned a1 = lbase + (unsigned)((((kg * 2 + 1) ^ xsw)) << 4);            \
        const unsigned a2 = lbase + (unsigned)((((kg * 2 + 8) ^ xsw)) << 4);            \
        const unsigned a3 = lbase + (unsigned)((((kg * 2 + 9) ^ xsw)) << 4);            \
        float4 xv0, xv1, xv2, xv3;                                                      \
        asm volatile("ds_read_b128 %0, %1" : "=&v"(xv0) : "v"(a0));                     \
        asm volatile("ds_read_b128 %0, %1" : "=&v"(xv1) : "v"(a1));                     \
        asm volatile("ds_read_b128 %0, %1" : "=&v"(xv2) : "v"(a2));                     \
        asm volatile("ds_read_b128 %0, %1" : "=&v"(xv3) : "v"(a3));                     \
        asm volatile("s_waitcnt lgkmcnt(0)" ::: "memory");                              \
        __builtin_amdgcn_sched_barrier(0);                                              \
        _Pragma("unroll")                                                               \
        for (int ks = 0; ks < 2; ++ks) {                                                \
            float4 x0 = ks ? xv2 : xv0;                                                 \
            float4 x1 = ks ? xv3 : xv1;                                                 \
            bf16x8 af;                                                                  \
            af[0] = (short)f2bf(x0.x); af[1] = (short)f2bf(x0.y);                       \
            af[2] = (short)f2bf(x0.z); af[3] = (short)f2bf(x0.w);                       \
            af[4] = (short)f2bf(x1.x); af[5] = (short)f2bf(x1.y);                       \
            af[6] = (short)f2bf(x1.z); af[7] = (short)f2bf(x1.w);                       \
            const ushort* bpp = packB + ((size_t)(((c) * 2 + ks) * 8) * 64 + lane) * 8; \
            _Pragma("unroll")                                                           \
            for (int cf = 0; cf < 8; ++cf) {                                            \
                bf16x8 bfv = *(const bf16x8*)(bpp + cf * 512);                          \
                acc[cf] = __builtin_amdgcn_mfma_f32_16x16x32_bf16(af, bfv, acc[cf], 0, 0, 0); \
            }                                                                           \
        }                                                                               \
    }

    // waits derived incl. 16 B-loads/chunk pollution (in-order retirement):
    G1_CHUNK(0, "8")
    G1_CHUNK(1, "24")
    G1_CHUNK(2, "40")
    G1_CHUNK(3, "40")
    G1_CHUNK(4, "40")
    G1_CHUNK(5, "40")
    G1_CHUNK(6, "36")
    G1_CHUNK(7, "32")
#undef G1_CHUNK

    // C/D: col = lane&15, row = (lane>>4)*4 + j   [m89-verified]
#pragma unroll
    for (int cf = 0; cf < 8; ++cf)
#pragma unroll
        for (int j = 0; j < 4; ++j)
            C[(size_t)(rowBase + kg * 4 + j) * NHID + cf * 16 + rl] = f2bf(acc[cf][j]);
}

// ---------------- GEMM2: xw2[50000x64](bf16) = h[50000x128](bf16) @ packW2 ----------------
__global__ __launch_bounds__(256) void gemm2_kernel(const ushort* __restrict__ A,
                                                    const ushort* __restrict__ packB,
                                                    ushort* __restrict__ C) {
    int wid = (blockIdx.x * blockDim.x + threadIdx.x) >> 6;
    int lane = threadIdx.x & 63;
    int rowBase = wid * 16;
    if (rowBase >= NNODES) return;
    int rl = lane & 15;
    int kg = lane >> 4;
    const ushort* ap = A + (size_t)(rowBase + rl) * NHID + kg * 8;

    f32x4 acc[4];
#pragma unroll
    for (int cf = 0; cf < 4; ++cf) acc[cf] = (f32x4)(0.f);

#pragma unroll
    for (int ks = 0; ks < 4; ++ks) {
        bf16x8 af = *(const bf16x8*)(ap + ks * 32);
        const ushort* bp = packB + ((size_t)(ks * 4) * 64 + lane) * 8;
#pragma unroll
        for (int cf = 0; cf < 4; ++cf) {
            bf16x8 bf = *(const bf16x8*)(bp + (size_t)cf * 512);
            acc[cf] = __builtin_amdgcn_mfma_f32_16x16x32_bf16(af, bf, acc[cf], 0, 0, 0);
        }
    }
#pragma unroll
    for (int cf = 0; cf < 4; ++cf)
#pragma unroll
        for (int j = 0; j < 4; ++j)
            C[(size_t)(rowBase + kg * 4 + j) * NCLS + cf * 16 + rl] = f2bf(acc[cf][j]);
}

// ---------------- agg1: h = relu(agg(xw1) + b1), one wave per node, bf16 in/out ----------------
__global__ __launch_bounds__(256) void agg1_kernel(const ushort* __restrict__ xw,
                                                   const int* __restrict__ rowptr,
                                                   const int2* __restrict__ csr,
                                                   const float* __restrict__ dinv,
                                                   const float* __restrict__ b1,
                                                   ushort* __restrict__ h) {
    int wid = (blockIdx.x * blockDim.x + threadIdx.x) >> 6;
    int lane = threadIdx.x & 63;
    if (wid >= NNODES) return;
    int beg = rowptr[wid], end = rowptr[wid + 1];
    float a0 = 0.f, a1 = 0.f;
    int j = beg;
    for (; j + 8 <= end; j += 8) {
        int2 e[8];
#pragma unroll
        for (int q = 0; q < 8; ++q) e[q] = csr[j + q];
        uint v[8];
#pragma unroll
        for (int q = 0; q < 8; ++q) v[q] = *(const uint*)&xw[(size_t)e[q].x * NHID + lane * 2];
#pragma unroll
        for (int q = 0; q < 8; ++q) {
            float wq = __int_as_float(e[q].y);
            a0 += wq * __uint_as_float(v[q] << 16);
            a1 += wq * __uint_as_float(v[q] & 0xffff0000u);
        }
    }
    for (; j < end; ++j) {
        int2 e = csr[j];
        float w = __int_as_float(e.y);
        uint v = *(const uint*)&xw[(size_t)e.x * NHID + lane * 2];
        a0 += w * __uint_as_float(v << 16);
        a1 += w * __uint_as_float(v & 0xffff0000u);
    }
    float di = dinv[wid];
    float sl = di * di;
    uint xv = *(const uint*)&xw[(size_t)wid * NHID + lane * 2];
    float2 bv = *(const float2*)&b1[lane * 2];
    float r0 = di * a0 + sl * __uint_as_float(xv << 16) + bv.x;
    float r1 = di * a1 + sl * __uint_as_float(xv & 0xffff0000u) + bv.y;
    uint o = (uint)f2bf(fmaxf(r0, 0.f)) | ((uint)f2bf(fmaxf(r1, 0.f)) << 16);
    *(uint*)&h[(size_t)wid * NHID + lane * 2] = o;
}

// ---------------- agg2 + bias + log_softmax, one wave per node, bf16 in, f32 out ----------------
__global__ __launch_bounds__(256) void agg2_kernel(const ushort* __restrict__ xw,
                                                   const int* __restrict__ rowptr,
                                                   const int2* __restrict__ csr,
                                                   const float* __restrict__ dinv,
                                                   const float* __restrict__ b2,
                                                   float* __restrict__ out) {
    int wid = (blockIdx.x * blockDim.x + threadIdx.x) >> 6;
    int lane = threadIdx.x & 63;
    if (wid >= NNODES) return;
    int beg = rowptr[wid], end = rowptr[wid + 1];
    float a = 0.f;
    int j = beg;
    for (; j + 8 <= end; j += 8) {
        int2 e[8];
#pragma unroll
        for (int q = 0; q < 8; ++q) e[q] = csr[j + q];
        float v[8];
#pragma unroll
        for (int q = 0; q < 8; ++q) v[q] = bf2f(xw[(size_t)e[q].x * NCLS + lane]);
#pragma unroll
        for (int q = 0; q < 8; ++q) a += __int_as_float(e[q].y) * v[q];
    }
    for (; j < end; ++j) {
        int2 e = csr[j];
        a += __int_as_float(e.y) * bf2f(xw[(size_t)e.x * NCLS + lane]);
    }
    float di = dinv[wid];
    float o = di * a + di * di * bf2f(xw[(size_t)wid * NCLS + lane]) + b2[lane];
    float m = o;
#pragma unroll
    for (int off = 32; off; off >>= 1) m = fmaxf(m, __shfl_xor(m, off, 64));
    float ex = __expf(o - m);
    float ssum = ex;
#pragma unroll
    for (int off = 32; off; off >>= 1) ssum += __shfl_xor(ssum, off, 64);
    out[(size_t)wid * NCLS + lane] = (o - m) - __logf(ssum);
}

// ---------------- launch ----------------

extern "C" void kernel_launch(void* const* d_in, const int* in_sizes, int n_in,
                              void* d_out, int out_size, void* d_ws, size_t ws_size,
                              hipStream_t stream) {
    const float* x  = (const float*)d_in[0];
    const int*   ei = (const int*)d_in[1];
    const int*   src = ei;
    const int*   dst = ei + NEDGES;
    const float* W1 = (const float*)d_in[2];
    const float* b1 = (const float*)d_in[3];
    const float* W2 = (const float*)d_in[4];
    const float* b2 = (const float*)d_in[5];
    float* out = (float*)d_out;

    char* w = (char*)d_ws;
    auto alloc = [&](size_t bytes) {
        char* p = w;
        w += (bytes + 255) & ~(size_t)255;
        return p;
    };
    int*    deg    = (int*)alloc((size_t)2 * NNODES * 4);  // deg + cursor (one clear)
    int*    cursor = deg + NNODES;
    int*    rowptr = (int*)alloc((NNODES + 1) * 4);
    int*    blkSum = (int*)alloc(SCAN_NB * 4);
    int2*   csr    = (int2*)alloc((size_t)NEDGES * 8);
    float*  dinv   = (float*)alloc(NNODES * 4);
    ushort* pack1  = (ushort*)alloc((size_t)16 * 8 * 64 * 8 * 2);
    ushort* pack2  = (ushort*)alloc((size_t)4 * 4 * 64 * 8 * 2);
    ushort* xw1    = (ushort*)alloc((size_t)NNODES * NHID * 2);
    ushort* h      = (ushort*)alloc((size_t)NNODES * NHID * 2);
    ushort* xw2    = (ushort*)alloc((size_t)NNODES * NCLS * 2);

    const int n4 = (2 * NNODES + 3) / 4;  // deg+cursor as int4
    clear_kernel<<<(n4 + 255) / 256, 256, 0, stream>>>((int4*)deg, n4);

    deg_kernel<<<(NEDGES + 255) / 256, 256, 0, stream>>>(dst, deg);
    scan1_kernel<<<SCAN_NB, SCAN_BLK, 0, stream>>>(deg, blkSum, dinv);
    scan2_kernel<<<1, 128, 0, stream>>>(blkSum, rowptr);
    scan3_kernel<<<SCAN_NB, SCAN_BLK, 0, stream>>>(deg, blkSum, rowptr);
    scatter_kernel<<<(NEDGES + 255) / 256, 256, 0, stream>>>(src, dst, rowptr, cursor, dinv, csr);

    pack_kernel<NHID, 16, 8><<<(16 * 8 * 64 * 8 + 255) / 256, 256, 0, stream>>>(W1, pack1);
    pack_kernel<NCLS, 4, 4><<<(4 * 4 * 64 * 8 + 255) / 256, 256, 0, stream>>>(W2, pack2);

    // layer 1 (1 wave/block, counted-vmcnt LDS pipeline, asm ds_read)
    gemm1_kernel<<<NNODES / 16, 64, 0, stream>>>(x, pack1, xw1);
    agg1_kernel<<<(NNODES * 64 + 255) / 256, 256, 0, stream>>>(xw1, rowptr, csr, dinv, b1, h);

    // layer 2 (+ fused bias + log_softmax)
    gemm2_kernel<<<(NNODES / 16 + 3) / 4, 256, 0, stream>>>(h, pack2, xw2);
    agg2_kernel<<<(NNODES * 64 + 255) / 256, 256, 0, stream>>>(xw2, rowptr, csr, dinv, b2, out);
}

// Round 11
// 204.766 us; speedup vs baseline: 1.0532x; 1.0309x over previous
//
#include <hip/hip_runtime.h>
#include <hip/hip_bf16.h>
#include <cstdint>
#include <cstddef>

#define NNODES 50000
#define NEDGES 800000
#define NIN    512
#define NHID   128
#define NCLS   64

#define SCAN_BLK 512
#define SCAN_NB ((NNODES + SCAN_BLK - 1) / SCAN_BLK)  // 98

typedef __attribute__((ext_vector_type(8))) short bf16x8;
typedef __attribute__((ext_vector_type(4))) float f32x4;

static __device__ __forceinline__ ushort f2bf(float f) {
    uint32_t u = __float_as_uint(f);
    uint32_t r = (u + 0x7fffu + ((u >> 16) & 1u)) >> 16;  // RNE
    return (ushort)r;
}
static __device__ __forceinline__ float bf2f(ushort b) {
    return __uint_as_float(((uint32_t)b) << 16);
}

// generic (LDS-backed) pointer -> 32-bit LDS byte offset for inline-asm ds_read
static __device__ __forceinline__ unsigned ldsAddr(const void* p) {
    return (unsigned)(size_t)(__attribute__((address_space(3))) const void*)p;
}

// ---------------- workspace clear ----------------
__global__ void clear_kernel(int4* __restrict__ p, int n4) {
    int i = blockIdx.x * blockDim.x + threadIdx.x;
    if (i < n4) p[i] = make_int4(0, 0, 0, 0);
}

// ---------------- CSR build ----------------

__global__ void deg_kernel(const int* __restrict__ dst, int* __restrict__ deg) {
    int e = blockIdx.x * blockDim.x + threadIdx.x;
    if (e < NEDGES) atomicAdd(&deg[dst[e]], 1);
}

// phase 1: per-block sums of deg; also compute dinv (fused)
__global__ __launch_bounds__(SCAN_BLK) void scan1_kernel(const int* __restrict__ deg,
                                                         int* __restrict__ blkSum,
                                                         float* __restrict__ dinv) {
    int i = blockIdx.x * SCAN_BLK + threadIdx.x;
    int d = (i < NNODES) ? deg[i] : 0;
    if (i < NNODES) dinv[i] = rsqrtf((float)d + 1.0f);
    int v = d;
#pragma unroll
    for (int off = 32; off; off >>= 1) v += __shfl_xor(v, off, 64);
    __shared__ int ws[SCAN_BLK / 64];
    int w = threadIdx.x >> 6;
    if ((threadIdx.x & 63) == 0) ws[w] = v;
    __syncthreads();
    if (threadIdx.x == 0) {
        int s = 0;
#pragma unroll
        for (int k = 0; k < SCAN_BLK / 64; ++k) s += ws[k];
        blkSum[blockIdx.x] = s;
    }
}

// phase 2: exclusive scan of the 98 block sums (single small block)
__global__ void scan2_kernel(int* __restrict__ blkSum, int* __restrict__ rowptr) {
    __shared__ int sh[128];
    int t = threadIdx.x;
    int v = (t < SCAN_NB) ? blkSum[t] : 0;
    sh[t] = v;
    __syncthreads();
    for (int off = 1; off < 128; off <<= 1) {
        int o = (t >= off) ? sh[t - off] : 0;
        __syncthreads();
        sh[t] += o;
        __syncthreads();
    }
    if (t < SCAN_NB) blkSum[t] = sh[t] - v;  // exclusive
    if (t == 0) rowptr[NNODES] = NEDGES;     // every edge has a dst
}

// phase 3: per-block exclusive scan + block offset -> rowptr
__global__ __launch_bounds__(SCAN_BLK) void scan3_kernel(const int* __restrict__ deg,
                                                         const int* __restrict__ blkOff,
                                                         int* __restrict__ rowptr) {
    int i = blockIdx.x * SCAN_BLK + threadIdx.x;
    int v = (i < NNODES) ? deg[i] : 0;
    int lane = threadIdx.x & 63;
    int w = threadIdx.x >> 6;
    int inc = v;
#pragma unroll
    for (int off = 1; off < 64; off <<= 1) {
        int o = __shfl_up(inc, off, 64);
        if (lane >= off) inc += o;
    }
    __shared__ int ws[SCAN_BLK / 64];
    if (lane == 63) ws[w] = inc;
    __syncthreads();
    int wpre = 0;
    for (int k = 0; k < w; ++k) wpre += ws[k];
    if (i < NNODES) rowptr[i] = inc - v + wpre + blkOff[blockIdx.x];
}

__global__ void scatter_kernel(const int* __restrict__ src, const int* __restrict__ dst,
                               const int* __restrict__ rowptr, int* __restrict__ cursor,
                               const float* __restrict__ dinv, int2* __restrict__ csr) {
    int e = blockIdx.x * blockDim.x + threadIdx.x;
    if (e >= NEDGES) return;
    int d = dst[e];
    int s = src[e];
    int pos = rowptr[d] + atomicAdd(&cursor[d], 1);
    csr[pos] = make_int2(s, __float_as_int(dinv[s]));
}

// ---------------- W pre-pack into MFMA B-fragment order (bf16) ----------------
template <int NOUT, int KS, int CF>
__global__ void pack_kernel(const float* __restrict__ W, ushort* __restrict__ pack) {
    int t = blockIdx.x * blockDim.x + threadIdx.x;
    if (t >= KS * CF * 64 * 8) return;
    int j = t & 7;
    int lane = (t >> 3) & 63;
    int cf = (t >> 9) % CF;
    int ks = t / (CF * 512);
    int k = ks * 32 + (lane >> 4) * 8 + j;
    int c = cf * 16 + (lane & 15);
    pack[t] = f2bf(W[(size_t)k * NOUT + c]);
}

// ---------------- GEMM1: xw1[50000x128](bf16) = x[50000x512](f32) @ packW1 ----------------
// KEY FIX (rounds 5-10 invariant): per-chunk B-loads from global, consumed by same-chunk
// MFMA, forced an effective vmcnt(0) drain every chunk (in-order vmcnt retirement: waiting
// for the NEWEST load retires all older staged loads too). Now each wave PRELOADS all its
// B fragments (16 ks x 2 cf = 128 VGPR) before the K-loop -> the loop's only VMEM is the
// A staging. A is reg-staged (T14 issue-early/write-late) into 2x8KB bf16 LDS with XOR
// swizzle (conflict-free b128 both sides, verified); f32->bf16 cvt happens at stage time,
// so compute phase is pure {asm ds_read -> lgkmcnt -> MFMA}. 2-phase raw s_barrier.
__global__ __launch_bounds__(256, 2) void gemm1_kernel(const float* __restrict__ A,
                                                       const ushort* __restrict__ packB,
                                                       ushort* __restrict__ C) {
    __shared__ ushort lds[2][64 * 64];  // bf16: 2 x 8 KB
    const int t = threadIdx.x;
    const int lane = t & 63;
    const int w = t >> 6;
    const int rowBase = blockIdx.x * 64;
    const int rl = lane & 15;
    const int kg = lane >> 4;

    // ---- B preload: wave w owns cf = {2w, 2w+1}, all 16 k-steps (128 VGPR) ----
    bf16x8 bw[16][2];
    {
        const ushort* bbase = packB + (size_t)lane * 8;
#pragma unroll
        for (int ks = 0; ks < 16; ++ks)
#pragma unroll
            for (int q = 0; q < 2; ++q)
                bw[ks][q] = *(const bf16x8*)(bbase + ks * 4096 + (2 * w + q) * 512);
    }

    f32x4 acc[4][2];
#pragma unroll
    for (int rg = 0; rg < 4; ++rg)
#pragma unroll
        for (int q = 0; q < 2; ++q) acc[rg][q] = (f32x4)(0.f);

    // ---- staging addressing: 512 16B-blocks/chunk, 2 per thread ----
    // idx = t + i*256: row = idx>>3, cb = idx&7 (logical 16B block = 8 bf16 = 8 k-values)
    const int r0 = t >> 3,         c0 = t & 7;
    const int r1 = (t + 256) >> 3, c1 = (t + 256) & 7;
    int g0 = rowBase + r0; if (g0 >= NNODES) g0 = NNODES - 1;
    int g1 = rowBase + r1; if (g1 >= NNODES) g1 = NNODES - 1;
    const float* ga0 = A + (size_t)g0 * NIN + c0 * 8;
    const float* ga1 = A + (size_t)g1 * NIN + c1 * 8;
    ushort* wd0 = &lds[0][0] + r0 * 64 + ((c0 ^ (r0 & 7)) * 8);  // swizzled dest (ushort units)
    ushort* wd1 = &lds[0][0] + r1 * 64 + ((c1 ^ (r1 & 7)) * 8);

    auto cvt8 = [](float4 a, float4 b) {
        bf16x8 v;
        v[0] = (short)f2bf(a.x); v[1] = (short)f2bf(a.y);
        v[2] = (short)f2bf(a.z); v[3] = (short)f2bf(a.w);
        v[4] = (short)f2bf(b.x); v[5] = (short)f2bf(b.y);
        v[6] = (short)f2bf(b.z); v[7] = (short)f2bf(b.w);
        return v;
    };

    // ---- prologue: stage chunk 0 ----
    {
        float4 p0 = *(const float4*)(ga0);
        float4 p1 = *(const float4*)(ga0 + 4);
        float4 p2 = *(const float4*)(ga1);
        float4 p3 = *(const float4*)(ga1 + 4);
        *(bf16x8*)wd0 = cvt8(p0, p1);
        *(bf16x8*)wd1 = cvt8(p2, p3);
    }
    asm volatile("s_waitcnt lgkmcnt(0)" ::: "memory");
    __builtin_amdgcn_s_barrier();

#pragma unroll
    for (int tch = 0; tch < 8; ++tch) {
        const int cur = tch & 1;
        // phase A: issue next chunk's global reads (latency hides under phase B)
        float4 p0, p1, p2, p3;
        if (tch < 7) {
            p0 = *(const float4*)(ga0 + (tch + 1) * 64);
            p1 = *(const float4*)(ga0 + (tch + 1) * 64 + 4);
            p2 = *(const float4*)(ga1 + (tch + 1) * 64);
            p3 = *(const float4*)(ga1 + (tch + 1) * 64 + 4);
            __builtin_amdgcn_sched_barrier(0);  // pin load issue before compute
        }
        // phase B: compute on buf[cur] — pure ds_read+MFMA, zero in-loop VMEM waits
        const unsigned lbase = ldsAddr(&lds[cur][0]);
#pragma unroll
        for (int ks = 0; ks < 2; ++ks) {
            bf16x8 af0, af1, af2, af3;
            const unsigned sw = (unsigned)(((ks * 4 + kg) ^ (rl & 7)) * 16);
            const unsigned a0 = lbase + (unsigned)((0 * 16 + rl) * 128) + sw;
            const unsigned a1 = lbase + (unsigned)((1 * 16 + rl) * 128) + sw;
            const unsigned a2 = lbase + (unsigned)((2 * 16 + rl) * 128) + sw;
            const unsigned a3 = lbase + (unsigned)((3 * 16 + rl) * 128) + sw;
            asm volatile("ds_read_b128 %0, %1" : "=&v"(af0) : "v"(a0));
            asm volatile("ds_read_b128 %0, %1" : "=&v"(af1) : "v"(a1));
            asm volatile("ds_read_b128 %0, %1" : "=&v"(af2) : "v"(a2));
            asm volatile("ds_read_b128 %0, %1" : "=&v"(af3) : "v"(a3));
            asm volatile("s_waitcnt lgkmcnt(0)" ::: "memory");
            __builtin_amdgcn_sched_barrier(0);  // rule #18: MFMA must not hoist past wait
            const int kq = tch * 2 + ks;
            acc[0][0] = __builtin_amdgcn_mfma_f32_16x16x32_bf16(af0, bw[kq][0], acc[0][0], 0, 0, 0);
            acc[0][1] = __builtin_amdgcn_mfma_f32_16x16x32_bf16(af0, bw[kq][1], acc[0][1], 0, 0, 0);
            acc[1][0] = __builtin_amdgcn_mfma_f32_16x16x32_bf16(af1, bw[kq][0], acc[1][0], 0, 0, 0);
            acc[1][1] = __builtin_amdgcn_mfma_f32_16x16x32_bf16(af1, bw[kq][1], acc[1][1], 0, 0, 0);
            acc[2][0] = __builtin_amdgcn_mfma_f32_16x16x32_bf16(af2, bw[kq][0], acc[2][0], 0, 0, 0);
            acc[2][1] = __builtin_amdgcn_mfma_f32_16x16x32_bf16(af2, bw[kq][1], acc[2][1], 0, 0, 0);
            acc[3][0] = __builtin_amdgcn_mfma_f32_16x16x32_bf16(af3, bw[kq][0], acc[3][0], 0, 0, 0);
            acc[3][1] = __builtin_amdgcn_mfma_f32_16x16x32_bf16(af3, bw[kq][1], acc[3][1], 0, 0, 0);
        }
        // phase C: cvt + write next buf (compiler's vmcnt wait for p0..p3 lands here)
        if (tch < 7) {
            const int nxt = cur ^ 1;
            *(bf16x8*)(wd0 + nxt * 4096) = cvt8(p0, p1);
            *(bf16x8*)(wd1 + nxt * 4096) = cvt8(p2, p3);
        }
        asm volatile("s_waitcnt lgkmcnt(0)" ::: "memory");
        __builtin_amdgcn_s_barrier();
    }

    // C/D: col = lane&15, row = (lane>>4)*4 + j   [m89-verified]
#pragma unroll
    for (int rg = 0; rg < 4; ++rg)
#pragma unroll
        for (int q = 0; q < 2; ++q)
#pragma unroll
            for (int j = 0; j < 4; ++j) {
                int rr = rowBase + rg * 16 + kg * 4 + j;
                if (rr < NNODES)
                    C[(size_t)rr * NHID + (2 * w + q) * 16 + rl] = f2bf(acc[rg][q][j]);
            }
}

// ---------------- GEMM2: xw2[50000x64](bf16) = h[50000x128](bf16) @ packW2 ----------------
__global__ __launch_bounds__(256) void gemm2_kernel(const ushort* __restrict__ A,
                                                    const ushort* __restrict__ packB,
                                                    ushort* __restrict__ C) {
    int wid = (blockIdx.x * blockDim.x + threadIdx.x) >> 6;
    int lane = threadIdx.x & 63;
    int rowBase = wid * 16;
    if (rowBase >= NNODES) return;
    int rl = lane & 15;
    int kg = lane >> 4;
    const ushort* ap = A + (size_t)(rowBase + rl) * NHID + kg * 8;

    f32x4 acc[4];
#pragma unroll
    for (int cf = 0; cf < 4; ++cf) acc[cf] = (f32x4)(0.f);

#pragma unroll
    for (int ks = 0; ks < 4; ++ks) {
        bf16x8 af = *(const bf16x8*)(ap + ks * 32);
        const ushort* bp = packB + ((size_t)(ks * 4) * 64 + lane) * 8;
#pragma unroll
        for (int cf = 0; cf < 4; ++cf) {
            bf16x8 bf = *(const bf16x8*)(bp + (size_t)cf * 512);
            acc[cf] = __builtin_amdgcn_mfma_f32_16x16x32_bf16(af, bf, acc[cf], 0, 0, 0);
        }
    }
#pragma unroll
    for (int cf = 0; cf < 4; ++cf)
#pragma unroll
        for (int j = 0; j < 4; ++j)
            C[(size_t)(rowBase + kg * 4 + j) * NCLS + cf * 16 + rl] = f2bf(acc[cf][j]);
}

// ---------------- agg1: h = relu(agg(xw1) + b1), one wave per node, bf16 in/out ----------------
__global__ __launch_bounds__(256) void agg1_kernel(const ushort* __restrict__ xw,
                                                   const int* __restrict__ rowptr,
                                                   const int2* __restrict__ csr,
                                                   const float* __restrict__ dinv,
                                                   const float* __restrict__ b1,
                                                   ushort* __restrict__ h) {
    int wid = (blockIdx.x * blockDim.x + threadIdx.x) >> 6;
    int lane = threadIdx.x & 63;
    if (wid >= NNODES) return;
    int beg = rowptr[wid], end = rowptr[wid + 1];
    float a0 = 0.f, a1 = 0.f;
    int j = beg;
    for (; j + 8 <= end; j += 8) {
        int2 e[8];
#pragma unroll
        for (int q = 0; q < 8; ++q) e[q] = csr[j + q];
        uint v[8];
#pragma unroll
        for (int q = 0; q < 8; ++q) v[q] = *(const uint*)&xw[(size_t)e[q].x * NHID + lane * 2];
#pragma unroll
        for (int q = 0; q < 8; ++q) {
            float wq = __int_as_float(e[q].y);
            a0 += wq * __uint_as_float(v[q] << 16);
            a1 += wq * __uint_as_float(v[q] & 0xffff0000u);
        }
    }
    for (; j < end; ++j) {
        int2 e = csr[j];
        float w = __int_as_float(e.y);
        uint v = *(const uint*)&xw[(size_t)e.x * NHID + lane * 2];
        a0 += w * __uint_as_float(v << 16);
        a1 += w * __uint_as_float(v & 0xffff0000u);
    }
    float di = dinv[wid];
    float sl = di * di;
    uint xv = *(const uint*)&xw[(size_t)wid * NHID + lane * 2];
    float2 bv = *(const float2*)&b1[lane * 2];
    float r0 = di * a0 + sl * __uint_as_float(xv << 16) + bv.x;
    float r1 = di * a1 + sl * __uint_as_float(xv & 0xffff0000u) + bv.y;
    uint o = (uint)f2bf(fmaxf(r0, 0.f)) | ((uint)f2bf(fmaxf(r1, 0.f)) << 16);
    *(uint*)&h[(size_t)wid * NHID + lane * 2] = o;
}

// ---------------- agg2 + bias + log_softmax, one wave per node, bf16 in, f32 out ----------------
__global__ __launch_bounds__(256) void agg2_kernel(const ushort* __restrict__ xw,
                                                   const int* __restrict__ rowptr,
                                                   const int2* __restrict__ csr,
                                                   const float* __restrict__ dinv,
                                                   const float* __restrict__ b2,
                                                   float* __restrict__ out) {
    int wid = (blockIdx.x * blockDim.x + threadIdx.x) >> 6;
    int lane = threadIdx.x & 63;
    if (wid >= NNODES) return;
    int beg = rowptr[wid], end = rowptr[wid + 1];
    float a = 0.f;
    int j = beg;
    for (; j + 8 <= end; j += 8) {
        int2 e[8];
#pragma unroll
        for (int q = 0; q < 8; ++q) e[q] = csr[j + q];
        float v[8];
#pragma unroll
        for (int q = 0; q < 8; ++q) v[q] = bf2f(xw[(size_t)e[q].x * NCLS + lane]);
#pragma unroll
        for (int q = 0; q < 8; ++q) a += __int_as_float(e[q].y) * v[q];
    }
    for (; j < end; ++j) {
        int2 e = csr[j];
        a += __int_as_float(e.y) * bf2f(xw[(size_t)e.x * NCLS + lane]);
    }
    float di = dinv[wid];
    float o = di * a + di * di * bf2f(xw[(size_t)wid * NCLS + lane]) + b2[lane];
    float m = o;
#pragma unroll
    for (int off = 32; off; off >>= 1) m = fmaxf(m, __shfl_xor(m, off, 64));
    float ex = __expf(o - m);
    float ssum = ex;
#pragma unroll
    for (int off = 32; off; off >>= 1) ssum += __shfl_xor(ssum, off, 64);
    out[(size_t)wid * NCLS + lane] = (o - m) - __logf(ssum);
}

// ---------------- launch ----------------

extern "C" void kernel_launch(void* const* d_in, const int* in_sizes, int n_in,
                              void* d_out, int out_size, void* d_ws, size_t ws_size,
                              hipStream_t stream) {
    const float* x  = (const float*)d_in[0];
    const int*   ei = (const int*)d_in[1];
    const int*   src = ei;
    const int*   dst = ei + NEDGES;
    const float* W1 = (const float*)d_in[2];
    const float* b1 = (const float*)d_in[3];
    const float* W2 = (const float*)d_in[4];
    const float* b2 = (const float*)d_in[5];
    float* out = (float*)d_out;

    char* w = (char*)d_ws;
    auto alloc = [&](size_t bytes) {
        char* p = w;
        w += (bytes + 255) & ~(size_t)255;
        return p;
    };
    int*    deg    = (int*)alloc((size_t)2 * NNODES * 4);  // deg + cursor (one clear)
    int*    cursor = deg + NNODES;
    int*    rowptr = (int*)alloc((NNODES + 1) * 4);
    int*    blkSum = (int*)alloc(SCAN_NB * 4);
    int2*   csr    = (int2*)alloc((size_t)NEDGES * 8);
    float*  dinv   = (float*)alloc(NNODES * 4);
    ushort* pack1  = (ushort*)alloc((size_t)16 * 8 * 64 * 8 * 2);
    ushort* pack2  = (ushort*)alloc((size_t)4 * 4 * 64 * 8 * 2);
    ushort* xw1    = (ushort*)alloc((size_t)NNODES * NHID * 2);
    ushort* h      = (ushort*)alloc((size_t)NNODES * NHID * 2);
    ushort* xw2    = (ushort*)alloc((size_t)NNODES * NCLS * 2);

    const int n4 = (2 * NNODES + 3) / 4;  // deg+cursor as int4
    clear_kernel<<<(n4 + 255) / 256, 256, 0, stream>>>((int4*)deg, n4);

    deg_kernel<<<(NEDGES + 255) / 256, 256, 0, stream>>>(dst, deg);
    scan1_kernel<<<SCAN_NB, SCAN_BLK, 0, stream>>>(deg, blkSum, dinv);
    scan2_kernel<<<1, 128, 0, stream>>>(blkSum, rowptr);
    scan3_kernel<<<SCAN_NB, SCAN_BLK, 0, stream>>>(deg, blkSum, rowptr);
    scatter_kernel<<<(NEDGES + 255) / 256, 256, 0, stream>>>(src, dst, rowptr, cursor, dinv, csr);

    pack_kernel<NHID, 16, 8><<<(16 * 8 * 64 * 8 + 255) / 256, 256, 0, stream>>>(W1, pack1);
    pack_kernel<NCLS, 4, 4><<<(4 * 4 * 64 * 8 + 255) / 256, 256, 0, stream>>>(W2, pack2);

    // layer 1 (B-in-regs, reg-staged bf16 LDS, 2-phase)
    gemm1_kernel<<<(NNODES + 63) / 64, 256, 0, stream>>>(x, pack1, xw1);
    agg1_kernel<<<(NNODES * 64 + 255) / 256, 256, 0, stream>>>(xw1, rowptr, csr, dinv, b1, h);

    // layer 2 (+ fused bias + log_softmax)
    gemm2_kernel<<<(NNODES / 16 + 3) / 4, 256, 0, stream>>>(h, pack2, xw2);
    agg2_kernel<<<(NNODES * 64 + 255) / 256, 256, 0, stream>>>(xw2, rowptr, csr, dinv, b2, out);
}

// Round 12
// 193.869 us; speedup vs baseline: 1.1124x; 1.0562x over previous
//
#include <hip/hip_runtime.h>
#include <hip/hip_bf16.h>
#include <hip/hip_fp16.h>
#include <cstdint>
#include <cstddef>

#define NNODES 50000
#define NEDGES 800000
#define NIN    512
#define NHID   128
#define NCLS   64

#define SCAN_BLK 512
#define SCAN_NB ((NNODES + SCAN_BLK - 1) / SCAN_BLK)  // 98

typedef __attribute__((ext_vector_type(8))) short bf16x8;
typedef __attribute__((ext_vector_type(4))) float f32x4;

static __device__ __forceinline__ ushort f2bf(float f) {
    uint32_t u = __float_as_uint(f);
    uint32_t r = (u + 0x7fffu + ((u >> 16) & 1u)) >> 16;  // RNE
    return (ushort)r;
}
static __device__ __forceinline__ float bf2f(ushort b) {
    return __uint_as_float(((uint32_t)b) << 16);
}
static __device__ __forceinline__ float h2f(ushort u) {
    _Float16 h;
    __builtin_memcpy(&h, &u, 2);
    return (float)h;
}
static __device__ __forceinline__ ushort f2h(float f) {
    _Float16 h = (_Float16)f;
    ushort u;
    __builtin_memcpy(&u, &h, 2);
    return u;
}

// generic (LDS-backed) pointer -> 32-bit LDS byte offset for inline-asm ds_read
static __device__ __forceinline__ unsigned ldsAddr(const void* p) {
    return (unsigned)(size_t)(__attribute__((address_space(3))) const void*)p;
}

// ---------------- workspace clear ----------------
__global__ void clear_kernel(int4* __restrict__ p, int n4) {
    int i = blockIdx.x * blockDim.x + threadIdx.x;
    if (i < n4) p[i] = make_int4(0, 0, 0, 0);
}

// ---------------- CSR build ----------------

// 4 edges per thread, int4 coalesced dst read
__global__ void deg_kernel(const int4* __restrict__ dst4, int* __restrict__ deg) {
    int i = blockIdx.x * blockDim.x + threadIdx.x;
    if (i < NEDGES / 4) {
        int4 d = dst4[i];
        atomicAdd(&deg[d.x], 1);
        atomicAdd(&deg[d.y], 1);
        atomicAdd(&deg[d.z], 1);
        atomicAdd(&deg[d.w], 1);
    }
}

// phase 1: per-block sums of deg; also compute dinv (fused)
__global__ __launch_bounds__(SCAN_BLK) void scan1_kernel(const int* __restrict__ deg,
                                                         int* __restrict__ blkSum,
                                                         float* __restrict__ dinv) {
    int i = blockIdx.x * SCAN_BLK + threadIdx.x;
    int d = (i < NNODES) ? deg[i] : 0;
    if (i < NNODES) dinv[i] = rsqrtf((float)d + 1.0f);
    int v = d;
#pragma unroll
    for (int off = 32; off; off >>= 1) v += __shfl_xor(v, off, 64);
    __shared__ int ws[SCAN_BLK / 64];
    int w = threadIdx.x >> 6;
    if ((threadIdx.x & 63) == 0) ws[w] = v;
    __syncthreads();
    if (threadIdx.x == 0) {
        int s = 0;
#pragma unroll
        for (int k = 0; k < SCAN_BLK / 64; ++k) s += ws[k];
        blkSum[blockIdx.x] = s;
    }
}

// phase 2: exclusive scan of the 98 block sums (single small block)
__global__ void scan2_kernel(int* __restrict__ blkSum, int* __restrict__ rowptr) {
    __shared__ int sh[128];
    int t = threadIdx.x;
    int v = (t < SCAN_NB) ? blkSum[t] : 0;
    sh[t] = v;
    __syncthreads();
    for (int off = 1; off < 128; off <<= 1) {
        int o = (t >= off) ? sh[t - off] : 0;
        __syncthreads();
        sh[t] += o;
        __syncthreads();
    }
    if (t < SCAN_NB) blkSum[t] = sh[t] - v;  // exclusive
    if (t == 0) rowptr[NNODES] = NEDGES;     // every edge has a dst
}

// phase 3: per-block exclusive scan + block offset -> rowptr AND cursor (= rowptr copy)
__global__ __launch_bounds__(SCAN_BLK) void scan3_kernel(const int* __restrict__ deg,
                                                         const int* __restrict__ blkOff,
                                                         int* __restrict__ rowptr,
                                                         int* __restrict__ cursor) {
    int i = blockIdx.x * SCAN_BLK + threadIdx.x;
    int v = (i < NNODES) ? deg[i] : 0;
    int lane = threadIdx.x & 63;
    int w = threadIdx.x >> 6;
    int inc = v;
#pragma unroll
    for (int off = 1; off < 64; off <<= 1) {
        int o = __shfl_up(inc, off, 64);
        if (lane >= off) inc += o;
    }
    __shared__ int ws[SCAN_BLK / 64];
    if (lane == 63) ws[w] = inc;
    __syncthreads();
    int wpre = 0;
    for (int k = 0; k < w; ++k) wpre += ws[k];
    if (i < NNODES) {
        int rp = inc - v + wpre + blkOff[blockIdx.x];
        rowptr[i] = rp;
        cursor[i] = rp;  // scatter uses atomicAdd(&cursor[d],1) as absolute slot
    }
}

// csr entry: u16 src | fp16 dinv[src] << 16  (4 B/edge)
__global__ void scatter_kernel(const int* __restrict__ src, const int* __restrict__ dst,
                               int* __restrict__ cursor,
                               const float* __restrict__ dinv, uint* __restrict__ csr) {
    int e = blockIdx.x * blockDim.x + threadIdx.x;
    if (e >= NEDGES) return;
    int d = dst[e];
    int s = src[e];
    int pos = atomicAdd(&cursor[d], 1);
    csr[pos] = (uint)s | ((uint)f2h(dinv[s]) << 16);
}

// ---------------- W pre-pack into MFMA B-fragment order (bf16), both layers fused ----------------
__global__ void pack_kernel(const float* __restrict__ W1, const float* __restrict__ W2,
                            ushort* __restrict__ p1, ushort* __restrict__ p2) {
    int t = blockIdx.x * blockDim.x + threadIdx.x;
    const int N1 = 16 * 8 * 64 * 8;  // 65536
    if (t < N1) {
        int j = t & 7;
        int lane = (t >> 3) & 63;
        int cf = (t >> 9) & 7;
        int ks = t >> 12;
        int k = ks * 32 + (lane >> 4) * 8 + j;
        int c = cf * 16 + (lane & 15);
        p1[t] = f2bf(W1[(size_t)k * NHID + c]);
    } else {
        int u = t - N1;
        if (u < 4 * 4 * 64 * 8) {
            int j = u & 7;
            int lane = (u >> 3) & 63;
            int cf = (u >> 9) & 3;
            int ks = u >> 11;
            int k = ks * 32 + (lane >> 4) * 8 + j;
            int c = cf * 16 + (lane & 15);
            p2[u] = f2bf(W2[(size_t)k * NCLS + c]);
        }
    }
}

// ---------------- GEMM1: xw1[50000x128](bf16) = x[50000x512](f32) @ packW1 ----------------
// B fragments preloaded to VGPRs (no in-loop global B loads -> no forced vmcnt drains);
// A reg-staged (issue-early/write-late) into 2x8KB bf16 LDS, XOR-swizzled, asm ds_read.
__global__ __launch_bounds__(256, 2) void gemm1_kernel(const float* __restrict__ A,
                                                       const ushort* __restrict__ packB,
                                                       ushort* __restrict__ C) {
    __shared__ ushort lds[2][64 * 64];  // bf16: 2 x 8 KB
    const int t = threadIdx.x;
    const int lane = t & 63;
    const int w = t >> 6;
    const int rowBase = blockIdx.x * 64;
    const int rl = lane & 15;
    const int kg = lane >> 4;

    // ---- B preload: wave w owns cf = {2w, 2w+1}, all 16 k-steps (128 VGPR) ----
    bf16x8 bw[16][2];
    {
        const ushort* bbase = packB + (size_t)lane * 8;
#pragma unroll
        for (int ks = 0; ks < 16; ++ks)
#pragma unroll
            for (int q = 0; q < 2; ++q)
                bw[ks][q] = *(const bf16x8*)(bbase + ks * 4096 + (2 * w + q) * 512);
    }

    f32x4 acc[4][2];
#pragma unroll
    for (int rg = 0; rg < 4; ++rg)
#pragma unroll
        for (int q = 0; q < 2; ++q) acc[rg][q] = (f32x4)(0.f);

    const int r0 = t >> 3,         c0 = t & 7;
    const int r1 = (t + 256) >> 3, c1 = (t + 256) & 7;
    int g0 = rowBase + r0; if (g0 >= NNODES) g0 = NNODES - 1;
    int g1 = rowBase + r1; if (g1 >= NNODES) g1 = NNODES - 1;
    const float* ga0 = A + (size_t)g0 * NIN + c0 * 8;
    const float* ga1 = A + (size_t)g1 * NIN + c1 * 8;
    ushort* wd0 = &lds[0][0] + r0 * 64 + ((c0 ^ (r0 & 7)) * 8);
    ushort* wd1 = &lds[0][0] + r1 * 64 + ((c1 ^ (r1 & 7)) * 8);

    auto cvt8 = [](float4 a, float4 b) {
        bf16x8 v;
        v[0] = (short)f2bf(a.x); v[1] = (short)f2bf(a.y);
        v[2] = (short)f2bf(a.z); v[3] = (short)f2bf(a.w);
        v[4] = (short)f2bf(b.x); v[5] = (short)f2bf(b.y);
        v[6] = (short)f2bf(b.z); v[7] = (short)f2bf(b.w);
        return v;
    };

    {
        float4 p0 = *(const float4*)(ga0);
        float4 p1 = *(const float4*)(ga0 + 4);
        float4 p2 = *(const float4*)(ga1);
        float4 p3 = *(const float4*)(ga1 + 4);
        *(bf16x8*)wd0 = cvt8(p0, p1);
        *(bf16x8*)wd1 = cvt8(p2, p3);
    }
    asm volatile("s_waitcnt lgkmcnt(0)" ::: "memory");
    __builtin_amdgcn_s_barrier();

#pragma unroll
    for (int tch = 0; tch < 8; ++tch) {
        const int cur = tch & 1;
        float4 p0, p1, p2, p3;
        if (tch < 7) {
            p0 = *(const float4*)(ga0 + (tch + 1) * 64);
            p1 = *(const float4*)(ga0 + (tch + 1) * 64 + 4);
            p2 = *(const float4*)(ga1 + (tch + 1) * 64);
            p3 = *(const float4*)(ga1 + (tch + 1) * 64 + 4);
            __builtin_amdgcn_sched_barrier(0);
        }
        const unsigned lbase = ldsAddr(&lds[cur][0]);
#pragma unroll
        for (int ks = 0; ks < 2; ++ks) {
            bf16x8 af0, af1, af2, af3;
            const unsigned sw = (unsigned)(((ks * 4 + kg) ^ (rl & 7)) * 16);
            const unsigned a0 = lbase + (unsigned)((0 * 16 + rl) * 128) + sw;
            const unsigned a1 = lbase + (unsigned)((1 * 16 + rl) * 128) + sw;
            const unsigned a2 = lbase + (unsigned)((2 * 16 + rl) * 128) + sw;
            const unsigned a3 = lbase + (unsigned)((3 * 16 + rl) * 128) + sw;
            asm volatile("ds_read_b128 %0, %1" : "=&v"(af0) : "v"(a0));
            asm volatile("ds_read_b128 %0, %1" : "=&v"(af1) : "v"(a1));
            asm volatile("ds_read_b128 %0, %1" : "=&v"(af2) : "v"(a2));
            asm volatile("ds_read_b128 %0, %1" : "=&v"(af3) : "v"(a3));
            asm volatile("s_waitcnt lgkmcnt(0)" ::: "memory");
            __builtin_amdgcn_sched_barrier(0);
            const int kq = tch * 2 + ks;
            acc[0][0] = __builtin_amdgcn_mfma_f32_16x16x32_bf16(af0, bw[kq][0], acc[0][0], 0, 0, 0);
            acc[0][1] = __builtin_amdgcn_mfma_f32_16x16x32_bf16(af0, bw[kq][1], acc[0][1], 0, 0, 0);
            acc[1][0] = __builtin_amdgcn_mfma_f32_16x16x32_bf16(af1, bw[kq][0], acc[1][0], 0, 0, 0);
            acc[1][1] = __builtin_amdgcn_mfma_f32_16x16x32_bf16(af1, bw[kq][1], acc[1][1], 0, 0, 0);
            acc[2][0] = __builtin_amdgcn_mfma_f32_16x16x32_bf16(af2, bw[kq][0], acc[2][0], 0, 0, 0);
            acc[2][1] = __builtin_amdgcn_mfma_f32_16x16x32_bf16(af2, bw[kq][1], acc[2][1], 0, 0, 0);
            acc[3][0] = __builtin_amdgcn_mfma_f32_16x16x32_bf16(af3, bw[kq][0], acc[3][0], 0, 0, 0);
            acc[3][1] = __builtin_amdgcn_mfma_f32_16x16x32_bf16(af3, bw[kq][1], acc[3][1], 0, 0, 0);
        }
        if (tch < 7) {
            const int nxt = cur ^ 1;
            *(bf16x8*)(wd0 + nxt * 4096) = cvt8(p0, p1);
            *(bf16x8*)(wd1 + nxt * 4096) = cvt8(p2, p3);
        }
        asm volatile("s_waitcnt lgkmcnt(0)" ::: "memory");
        __builtin_amdgcn_s_barrier();
    }

    // C/D: col = lane&15, row = (lane>>4)*4 + j   [m89-verified]
#pragma unroll
    for (int rg = 0; rg < 4; ++rg)
#pragma unroll
        for (int q = 0; q < 2; ++q)
#pragma unroll
            for (int j = 0; j < 4; ++j) {
                int rr = rowBase + rg * 16 + kg * 4 + j;
                if (rr < NNODES)
                    C[(size_t)rr * NHID + (2 * w + q) * 16 + rl] = f2bf(acc[rg][q][j]);
            }
}

// ---------------- GEMM2: xw2[50000x64](bf16) = h[50000x128](bf16) @ packW2 ----------------
__global__ __launch_bounds__(256) void gemm2_kernel(const ushort* __restrict__ A,
                                                    const ushort* __restrict__ packB,
                                                    ushort* __restrict__ C) {
    int wid = (blockIdx.x * blockDim.x + threadIdx.x) >> 6;
    int lane = threadIdx.x & 63;
    int rowBase = wid * 16;
    if (rowBase >= NNODES) return;
    int rl = lane & 15;
    int kg = lane >> 4;
    const ushort* ap = A + (size_t)(rowBase + rl) * NHID + kg * 8;

    f32x4 acc[4];
#pragma unroll
    for (int cf = 0; cf < 4; ++cf) acc[cf] = (f32x4)(0.f);

#pragma unroll
    for (int ks = 0; ks < 4; ++ks) {
        bf16x8 af = *(const bf16x8*)(ap + ks * 32);
        const ushort* bp = packB + ((size_t)(ks * 4) * 64 + lane) * 8;
#pragma unroll
        for (int cf = 0; cf < 4; ++cf) {
            bf16x8 bf = *(const bf16x8*)(bp + (size_t)cf * 512);
            acc[cf] = __builtin_amdgcn_mfma_f32_16x16x32_bf16(af, bf, acc[cf], 0, 0, 0);
        }
    }
#pragma unroll
    for (int cf = 0; cf < 4; ++cf)
#pragma unroll
        for (int j = 0; j < 4; ++j)
            C[(size_t)(rowBase + kg * 4 + j) * NCLS + cf * 16 + rl] = f2bf(acc[cf][j]);
}

// ---------------- agg1: h = relu(agg(xw1) + b1), one wave per node, bf16 in/out ----------------
__global__ __launch_bounds__(256) void agg1_kernel(const ushort* __restrict__ xw,
                                                   const int* __restrict__ rowptr,
                                                   const uint* __restrict__ csr,
                                                   const float* __restrict__ dinv,
                                                   const float* __restrict__ b1,
                                                   ushort* __restrict__ h) {
    int wid = (blockIdx.x * blockDim.x + threadIdx.x) >> 6;
    int lane = threadIdx.x & 63;
    if (wid >= NNODES) return;
    int beg = rowptr[wid], end = rowptr[wid + 1];
    float a0 = 0.f, a1 = 0.f, a2 = 0.f, a3 = 0.f;
    int j = beg;
    for (; j + 16 <= end; j += 16) {
        uint e[16];
#pragma unroll
        for (int q = 0; q < 16; ++q) e[q] = csr[j + q];
        uint v[16];
#pragma unroll
        for (int q = 0; q < 16; ++q)
            v[q] = *(const uint*)&xw[(size_t)(e[q] & 0xffffu) * NHID + lane * 2];
#pragma unroll
        for (int q = 0; q < 8; ++q) {
            float wq = h2f((ushort)(e[q] >> 16));
            a0 += wq * __uint_as_float(v[q] << 16);
            a1 += wq * __uint_as_float(v[q] & 0xffff0000u);
        }
#pragma unroll
        for (int q = 8; q < 16; ++q) {
            float wq = h2f((ushort)(e[q] >> 16));
            a2 += wq * __uint_as_float(v[q] << 16);
            a3 += wq * __uint_as_float(v[q] & 0xffff0000u);
        }
    }
    for (; j + 4 <= end; j += 4) {
        uint e[4];
#pragma unroll
        for (int q = 0; q < 4; ++q) e[q] = csr[j + q];
        uint v[4];
#pragma unroll
        for (int q = 0; q < 4; ++q)
            v[q] = *(const uint*)&xw[(size_t)(e[q] & 0xffffu) * NHID + lane * 2];
#pragma unroll
        for (int q = 0; q < 4; ++q) {
            float wq = h2f((ushort)(e[q] >> 16));
            a0 += wq * __uint_as_float(v[q] << 16);
            a1 += wq * __uint_as_float(v[q] & 0xffff0000u);
        }
    }
    for (; j < end; ++j) {
        uint e = csr[j];
        float wq = h2f((ushort)(e >> 16));
        uint v = *(const uint*)&xw[(size_t)(e & 0xffffu) * NHID + lane * 2];
        a0 += wq * __uint_as_float(v << 16);
        a1 += wq * __uint_as_float(v & 0xffff0000u);
    }
    a0 += a2; a1 += a3;
    float di = dinv[wid];
    float sl = di * di;
    uint xv = *(const uint*)&xw[(size_t)wid * NHID + lane * 2];
    float2 bv = *(const float2*)&b1[lane * 2];
    float r0 = di * a0 + sl * __uint_as_float(xv << 16) + bv.x;
    float r1 = di * a1 + sl * __uint_as_float(xv & 0xffff0000u) + bv.y;
    uint o = (uint)f2bf(fmaxf(r0, 0.f)) | ((uint)f2bf(fmaxf(r1, 0.f)) << 16);
    *(uint*)&h[(size_t)wid * NHID + lane * 2] = o;
}

// ---------------- agg2 + bias + log_softmax, one wave per node, bf16 in, f32 out ----------------
__global__ __launch_bounds__(256) void agg2_kernel(const ushort* __restrict__ xw,
                                                   const int* __restrict__ rowptr,
                                                   const uint* __restrict__ csr,
                                                   const float* __restrict__ dinv,
                                                   const float* __restrict__ b2,
                                                   float* __restrict__ out) {
    int wid = (blockIdx.x * blockDim.x + threadIdx.x) >> 6;
    int lane = threadIdx.x & 63;
    if (wid >= NNODES) return;
    int beg = rowptr[wid], end = rowptr[wid + 1];
    float a = 0.f, b = 0.f;
    int j = beg;
    for (; j + 16 <= end; j += 16) {
        uint e[16];
#pragma unroll
        for (int q = 0; q < 16; ++q) e[q] = csr[j + q];
        float v[16];
#pragma unroll
        for (int q = 0; q < 16; ++q)
            v[q] = bf2f(xw[(size_t)(e[q] & 0xffffu) * NCLS + lane]);
#pragma unroll
        for (int q = 0; q < 8; ++q) a += h2f((ushort)(e[q] >> 16)) * v[q];
#pragma unroll
        for (int q = 8; q < 16; ++q) b += h2f((ushort)(e[q] >> 16)) * v[q];
    }
    for (; j + 4 <= end; j += 4) {
        uint e[4];
#pragma unroll
        for (int q = 0; q < 4; ++q) e[q] = csr[j + q];
        float v[4];
#pragma unroll
        for (int q = 0; q < 4; ++q)
            v[q] = bf2f(xw[(size_t)(e[q] & 0xffffu) * NCLS + lane]);
#pragma unroll
        for (int q = 0; q < 4; ++q) a += h2f((ushort)(e[q] >> 16)) * v[q];
    }
    for (; j < end; ++j) {
        uint e = csr[j];
        a += h2f((ushort)(e >> 16)) * bf2f(xw[(size_t)(e & 0xffffu) * NCLS + lane]);
    }
    a += b;
    float di = dinv[wid];
    float o = di * a + di * di * bf2f(xw[(size_t)wid * NCLS + lane]) + b2[lane];
    float m = o;
#pragma unroll
    for (int off = 32; off; off >>= 1) m = fmaxf(m, __shfl_xor(m, off, 64));
    float ex = __expf(o - m);
    float ssum = ex;
#pragma unroll
    for (int off = 32; off; off >>= 1) ssum += __shfl_xor(ssum, off, 64);
    out[(size_t)wid * NCLS + lane] = (o - m) - __logf(ssum);
}

// ---------------- launch ----------------

extern "C" void kernel_launch(void* const* d_in, const int* in_sizes, int n_in,
                              void* d_out, int out_size, void* d_ws, size_t ws_size,
                              hipStream_t stream) {
    const float* x  = (const float*)d_in[0];
    const int*   ei = (const int*)d_in[1];
    const int*   src = ei;
    const int*   dst = ei + NEDGES;
    const float* W1 = (const float*)d_in[2];
    const float* b1 = (const float*)d_in[3];
    const float* W2 = (const float*)d_in[4];
    const float* b2 = (const float*)d_in[5];
    float* out = (float*)d_out;

    char* w = (char*)d_ws;
    auto alloc = [&](size_t bytes) {
        char* p = w;
        w += (bytes + 255) & ~(size_t)255;
        return p;
    };
    int*    deg    = (int*)alloc(NNODES * 4);
    int*    cursor = (int*)alloc(NNODES * 4);
    int*    rowptr = (int*)alloc((NNODES + 1) * 4);
    int*    blkSum = (int*)alloc(SCAN_NB * 4);
    uint*   csr    = (uint*)alloc((size_t)NEDGES * 4);
    float*  dinv   = (float*)alloc(NNODES * 4);
    ushort* pack1  = (ushort*)alloc((size_t)16 * 8 * 64 * 8 * 2);
    ushort* pack2  = (ushort*)alloc((size_t)4 * 4 * 64 * 8 * 2);
    ushort* xw1    = (ushort*)alloc((size_t)NNODES * NHID * 2);
    ushort* h      = (ushort*)alloc((size_t)NNODES * NHID * 2);
    ushort* xw2    = (ushort*)alloc((size_t)NNODES * NCLS * 2);

    const int n4 = (NNODES + 3) / 4;  // deg only (cursor is written by scan3)
    clear_kernel<<<(n4 + 255) / 256, 256, 0, stream>>>((int4*)deg, n4);

    deg_kernel<<<(NEDGES / 4 + 255) / 256, 256, 0, stream>>>((const int4*)dst, deg);
    scan1_kernel<<<SCAN_NB, SCAN_BLK, 0, stream>>>(deg, blkSum, dinv);
    scan2_kernel<<<1, 128, 0, stream>>>(blkSum, rowptr);
    scan3_kernel<<<SCAN_NB, SCAN_BLK, 0, stream>>>(deg, blkSum, rowptr, cursor);
    scatter_kernel<<<(NEDGES + 255) / 256, 256, 0, stream>>>(src, dst, cursor, dinv, csr);

    pack_kernel<<<(16 * 8 * 64 * 8 + 4 * 4 * 64 * 8 + 255) / 256, 256, 0, stream>>>(W1, W2, pack1, pack2);

    // layer 1 (B-in-regs, reg-staged bf16 LDS, 2-phase)
    gemm1_kernel<<<(NNODES + 63) / 64, 256, 0, stream>>>(x, pack1, xw1);
    agg1_kernel<<<(NNODES * 64 + 255) / 256, 256, 0, stream>>>(xw1, rowptr, csr, dinv, b1, h);

    // layer 2 (+ fused bias + log_softmax)
    gemm2_kernel<<<(NNODES / 16 + 3) / 4, 256, 0, stream>>>(h, pack2, xw2);
    agg2_kernel<<<(NNODES * 64 + 255) / 256, 256, 0, stream>>>(xw2, rowptr, csr, dinv, b2, out);
}

// Round 13
// 192.641 us; speedup vs baseline: 1.1195x; 1.0064x over previous
//
#include <hip/hip_runtime.h>
#include <hip/hip_bf16.h>
#include <hip/hip_fp16.h>
#include <cstdint>
#include <cstddef>

#define NNODES 50000
#define NEDGES 800000
#define NIN    512
#define NHID   128
#define NCLS   64

#define SCAN_BLK 512
#define SCAN_NB ((NNODES + SCAN_BLK - 1) / SCAN_BLK)  // 98

typedef __attribute__((ext_vector_type(8))) short bf16x8;
typedef __attribute__((ext_vector_type(4))) float f32x4;

static __device__ __forceinline__ ushort f2bf(float f) {
    uint32_t u = __float_as_uint(f);
    uint32_t r = (u + 0x7fffu + ((u >> 16) & 1u)) >> 16;  // RNE
    return (ushort)r;
}
static __device__ __forceinline__ float bf2f(ushort b) {
    return __uint_as_float(((uint32_t)b) << 16);
}
static __device__ __forceinline__ float h2f(ushort u) {
    _Float16 h;
    __builtin_memcpy(&h, &u, 2);
    return (float)h;
}
static __device__ __forceinline__ ushort f2h(float f) {
    _Float16 h = (_Float16)f;
    ushort u;
    __builtin_memcpy(&u, &h, 2);
    return u;
}

// generic (LDS-backed) pointer -> 32-bit LDS byte offset for inline-asm ds_read
static __device__ __forceinline__ unsigned ldsAddr(const void* p) {
    return (unsigned)(size_t)(__attribute__((address_space(3))) const void*)p;
}

// ---------------- workspace clear ----------------
__global__ void clear_kernel(int4* __restrict__ p, int n4) {
    int i = blockIdx.x * blockDim.x + threadIdx.x;
    if (i < n4) p[i] = make_int4(0, 0, 0, 0);
}

// ---------------- CSR build ----------------

// 4 edges per thread, int4 coalesced dst read
__global__ void deg_kernel(const int4* __restrict__ dst4, int* __restrict__ deg) {
    int i = blockIdx.x * blockDim.x + threadIdx.x;
    if (i < NEDGES / 4) {
        int4 d = dst4[i];
        atomicAdd(&deg[d.x], 1);
        atomicAdd(&deg[d.y], 1);
        atomicAdd(&deg[d.z], 1);
        atomicAdd(&deg[d.w], 1);
    }
}

// phase 1: per-block sums of deg; also compute dinv (fused)
__global__ __launch_bounds__(SCAN_BLK) void scan1_kernel(const int* __restrict__ deg,
                                                         int* __restrict__ blkSum,
                                                         float* __restrict__ dinv) {
    int i = blockIdx.x * SCAN_BLK + threadIdx.x;
    int d = (i < NNODES) ? deg[i] : 0;
    if (i < NNODES) dinv[i] = rsqrtf((float)d + 1.0f);
    int v = d;
#pragma unroll
    for (int off = 32; off; off >>= 1) v += __shfl_xor(v, off, 64);
    __shared__ int ws[SCAN_BLK / 64];
    int w = threadIdx.x >> 6;
    if ((threadIdx.x & 63) == 0) ws[w] = v;
    __syncthreads();
    if (threadIdx.x == 0) {
        int s = 0;
#pragma unroll
        for (int k = 0; k < SCAN_BLK / 64; ++k) s += ws[k];
        blkSum[blockIdx.x] = s;
    }
}

// phase 2+3 merged: wave 0 computes this block's offset from raw blkSum; then per-block
// exclusive scan -> rowptr AND cursor (cursor = rowptr copy for absolute-slot scatter)
__global__ __launch_bounds__(SCAN_BLK) void scan3_kernel(const int* __restrict__ deg,
                                                         const int* __restrict__ blkSum,
                                                         int* __restrict__ rowptr,
                                                         int* __restrict__ cursor) {
    __shared__ int ws[SCAN_BLK / 64];
    __shared__ int boffsh;
    const int lane = threadIdx.x & 63;
    const int w = threadIdx.x >> 6;
    if (w == 0) {
        int accu = 0;
        for (int k = lane; k < blockIdx.x; k += 64) accu += blkSum[k];
#pragma unroll
        for (int off = 32; off; off >>= 1) accu += __shfl_xor(accu, off, 64);
        if (lane == 0) boffsh = accu;
    }
    int i = blockIdx.x * SCAN_BLK + threadIdx.x;
    int v = (i < NNODES) ? deg[i] : 0;
    int inc = v;
#pragma unroll
    for (int off = 1; off < 64; off <<= 1) {
        int o = __shfl_up(inc, off, 64);
        if (lane >= off) inc += o;
    }
    if (lane == 63) ws[w] = inc;
    __syncthreads();
    int wpre = 0;
    for (int k = 0; k < w; ++k) wpre += ws[k];
    if (i < NNODES) {
        int rp = inc - v + wpre + boffsh;
        rowptr[i] = rp;
        cursor[i] = rp;
    }
    if (i == 0) rowptr[NNODES] = NEDGES;  // every edge has a dst
}

// csr entry: u16 src | fp16 dinv[src] << 16  (4 B/edge)
__global__ void scatter_kernel(const int* __restrict__ src, const int* __restrict__ dst,
                               int* __restrict__ cursor,
                               const float* __restrict__ dinv, uint* __restrict__ csr) {
    int e = blockIdx.x * blockDim.x + threadIdx.x;
    if (e >= NEDGES) return;
    int d = dst[e];
    int s = src[e];
    int pos = atomicAdd(&cursor[d], 1);
    csr[pos] = (uint)s | ((uint)f2h(dinv[s]) << 16);
}

// ---------------- W pre-pack into MFMA B-fragment order (bf16), both layers fused ----------------
__global__ void pack_kernel(const float* __restrict__ W1, const float* __restrict__ W2,
                            ushort* __restrict__ p1, ushort* __restrict__ p2) {
    int t = blockIdx.x * blockDim.x + threadIdx.x;
    const int N1 = 16 * 8 * 64 * 8;  // 65536
    if (t < N1) {
        int j = t & 7;
        int lane = (t >> 3) & 63;
        int cf = (t >> 9) & 7;
        int ks = t >> 12;
        int k = ks * 32 + (lane >> 4) * 8 + j;
        int c = cf * 16 + (lane & 15);
        p1[t] = f2bf(W1[(size_t)k * NHID + c]);
    } else {
        int u = t - N1;
        if (u < 4 * 4 * 64 * 8) {
            int j = u & 7;
            int lane = (u >> 3) & 63;
            int cf = (u >> 9) & 3;
            int ks = u >> 11;
            int k = ks * 32 + (lane >> 4) * 8 + j;
            int c = cf * 16 + (lane & 15);
            p2[u] = f2bf(W2[(size_t)k * NCLS + c]);
        }
    }
}

// ---------------- GEMM1: xw1[50000x128](bf16) = x[50000x512](f32) @ packW1 ----------------
// B fragments preloaded to VGPRs (no in-loop global B -> no forced drains). A reg-staged
// with a DEPTH-2 pipeline: phase A of iter c issues chunk c+2's loads; phase C writes
// chunk c+1 (issued a full iteration earlier -> ~2 phase-Bs of latency cover). Two
// statically-addressed pending sets pend[c&1] (full unroll -> compile-time indices).
// Compiler's per-register dataflow emits counted vmcnt(4) at phase C (newest 4 loads
// stay in flight). XOR-swizzled bf16 LDS, asm ds_read, rule-#18 fences.
__global__ __launch_bounds__(256, 2) void gemm1_kernel(const float* __restrict__ A,
                                                       const ushort* __restrict__ packB,
                                                       ushort* __restrict__ C) {
    __shared__ ushort lds[2][64 * 64];  // bf16: 2 x 8 KB
    const int t = threadIdx.x;
    const int lane = t & 63;
    const int w = t >> 6;
    const int rowBase = blockIdx.x * 64;
    const int rl = lane & 15;
    const int kg = lane >> 4;

    // ---- B preload: wave w owns cf = {2w, 2w+1}, all 16 k-steps (128 VGPR) ----
    bf16x8 bw[16][2];
    {
        const ushort* bbase = packB + (size_t)lane * 8;
#pragma unroll
        for (int ks = 0; ks < 16; ++ks)
#pragma unroll
            for (int q = 0; q < 2; ++q)
                bw[ks][q] = *(const bf16x8*)(bbase + ks * 4096 + (2 * w + q) * 512);
    }

    f32x4 acc[4][2];
#pragma unroll
    for (int rg = 0; rg < 4; ++rg)
#pragma unroll
        for (int q = 0; q < 2; ++q) acc[rg][q] = (f32x4)(0.f);

    const int r0 = t >> 3,         c0 = t & 7;
    const int r1 = (t + 256) >> 3, c1 = (t + 256) & 7;
    int g0 = rowBase + r0; if (g0 >= NNODES) g0 = NNODES - 1;
    int g1 = rowBase + r1; if (g1 >= NNODES) g1 = NNODES - 1;
    const float* ga0 = A + (size_t)g0 * NIN + c0 * 8;
    const float* ga1 = A + (size_t)g1 * NIN + c1 * 8;
    ushort* wd0 = &lds[0][0] + r0 * 64 + ((c0 ^ (r0 & 7)) * 8);
    ushort* wd1 = &lds[0][0] + r1 * 64 + ((c1 ^ (r1 & 7)) * 8);

    auto cvt8 = [](float4 a, float4 b) {
        bf16x8 v;
        v[0] = (short)f2bf(a.x); v[1] = (short)f2bf(a.y);
        v[2] = (short)f2bf(a.z); v[3] = (short)f2bf(a.w);
        v[4] = (short)f2bf(b.x); v[5] = (short)f2bf(b.y);
        v[6] = (short)f2bf(b.z); v[7] = (short)f2bf(b.w);
        return v;
    };

    // ---- prologue: issue chunk0 + chunk1 loads; write chunk0 to buf0 ----
    float4 pend[2][4];
    pend[0][0] = *(const float4*)(ga0);
    pend[0][1] = *(const float4*)(ga0 + 4);
    pend[0][2] = *(const float4*)(ga1);
    pend[0][3] = *(const float4*)(ga1 + 4);
    pend[1][0] = *(const float4*)(ga0 + 64);
    pend[1][1] = *(const float4*)(ga0 + 68);
    pend[1][2] = *(const float4*)(ga1 + 64);
    pend[1][3] = *(const float4*)(ga1 + 68);
    *(bf16x8*)wd0 = cvt8(pend[0][0], pend[0][1]);  // compiler: vmcnt(4) — chunk1 stays in flight
    *(bf16x8*)wd1 = cvt8(pend[0][2], pend[0][3]);
    asm volatile("s_waitcnt lgkmcnt(0)" ::: "memory");
    __builtin_amdgcn_s_barrier();

#pragma unroll
    for (int tch = 0; tch < 8; ++tch) {
        const int cur = tch & 1;
        // phase A: issue chunk tch+2 loads into pend[cur] (chunk tch's set, already in LDS)
        if (tch + 2 < 8) {
            pend[cur][0] = *(const float4*)(ga0 + (tch + 2) * 64);
            pend[cur][1] = *(const float4*)(ga0 + (tch + 2) * 64 + 4);
            pend[cur][2] = *(const float4*)(ga1 + (tch + 2) * 64);
            pend[cur][3] = *(const float4*)(ga1 + (tch + 2) * 64 + 4);
            __builtin_amdgcn_sched_barrier(0);  // pin issue before compute
        }
        // phase B: compute on buf[cur] — pure ds_read+MFMA
        const unsigned lbase = ldsAddr(&lds[cur][0]);
#pragma unroll
        for (int ks = 0; ks < 2; ++ks) {
            bf16x8 af0, af1, af2, af3;
            const unsigned sw = (unsigned)(((ks * 4 + kg) ^ (rl & 7)) * 16);
            const unsigned a0 = lbase + (unsigned)((0 * 16 + rl) * 128) + sw;
            const unsigned a1 = lbase + (unsigned)((1 * 16 + rl) * 128) + sw;
            const unsigned a2 = lbase + (unsigned)((2 * 16 + rl) * 128) + sw;
            const unsigned a3 = lbase + (unsigned)((3 * 16 + rl) * 128) + sw;
            asm volatile("ds_read_b128 %0, %1" : "=&v"(af0) : "v"(a0));
            asm volatile("ds_read_b128 %0, %1" : "=&v"(af1) : "v"(a1));
            asm volatile("ds_read_b128 %0, %1" : "=&v"(af2) : "v"(a2));
            asm volatile("ds_read_b128 %0, %1" : "=&v"(af3) : "v"(a3));
            asm volatile("s_waitcnt lgkmcnt(0)" ::: "memory");
            __builtin_amdgcn_sched_barrier(0);  // rule #18
            const int kq = tch * 2 + ks;
            acc[0][0] = __builtin_amdgcn_mfma_f32_16x16x32_bf16(af0, bw[kq][0], acc[0][0], 0, 0, 0);
            acc[0][1] = __builtin_amdgcn_mfma_f32_16x16x32_bf16(af0, bw[kq][1], acc[0][1], 0, 0, 0);
            acc[1][0] = __builtin_amdgcn_mfma_f32_16x16x32_bf16(af1, bw[kq][0], acc[1][0], 0, 0, 0);
            acc[1][1] = __builtin_amdgcn_mfma_f32_16x16x32_bf16(af1, bw[kq][1], acc[1][1], 0, 0, 0);
            acc[2][0] = __builtin_amdgcn_mfma_f32_16x16x32_bf16(af2, bw[kq][0], acc[2][0], 0, 0, 0);
            acc[2][1] = __builtin_amdgcn_mfma_f32_16x16x32_bf16(af2, bw[kq][1], acc[2][1], 0, 0, 0);
            acc[3][0] = __builtin_amdgcn_mfma_f32_16x16x32_bf16(af3, bw[kq][0], acc[3][0], 0, 0, 0);
            acc[3][1] = __builtin_amdgcn_mfma_f32_16x16x32_bf16(af3, bw[kq][1], acc[3][1], 0, 0, 0);
        }
        // phase C: write chunk tch+1 (loaded LAST iteration -> ~full iteration of cover);
        // compiler inserts vmcnt(4): only the newest (chunk tch+2) loads stay outstanding
        if (tch + 1 < 8) {
            const int nxt = cur ^ 1;
            *(bf16x8*)(wd0 + nxt * 4096) = cvt8(pend[nxt][0], pend[nxt][1]);
            *(bf16x8*)(wd1 + nxt * 4096) = cvt8(pend[nxt][2], pend[nxt][3]);
        }
        asm volatile("s_waitcnt lgkmcnt(0)" ::: "memory");
        __builtin_amdgcn_s_barrier();
    }

    // C/D: col = lane&15, row = (lane>>4)*4 + j   [m89-verified]
#pragma unroll
    for (int rg = 0; rg < 4; ++rg)
#pragma unroll
        for (int q = 0; q < 2; ++q)
#pragma unroll
            for (int j = 0; j < 4; ++j) {
                int rr = rowBase + rg * 16 + kg * 4 + j;
                if (rr < NNODES)
                    C[(size_t)rr * NHID + (2 * w + q) * 16 + rl] = f2bf(acc[rg][q][j]);
            }
}

// ---------------- GEMM2: xw2[50000x64](bf16) = h[50000x128](bf16) @ packW2 ----------------
__global__ __launch_bounds__(256) void gemm2_kernel(const ushort* __restrict__ A,
                                                    const ushort* __restrict__ packB,
                                                    ushort* __restrict__ C) {
    int wid = (blockIdx.x * blockDim.x + threadIdx.x) >> 6;
    int lane = threadIdx.x & 63;
    int rowBase = wid * 16;
    if (rowBase >= NNODES) return;
    int rl = lane & 15;
    int kg = lane >> 4;
    const ushort* ap = A + (size_t)(rowBase + rl) * NHID + kg * 8;

    f32x4 acc[4];
#pragma unroll
    for (int cf = 0; cf < 4; ++cf) acc[cf] = (f32x4)(0.f);

#pragma unroll
    for (int ks = 0; ks < 4; ++ks) {
        bf16x8 af = *(const bf16x8*)(ap + ks * 32);
        const ushort* bp = packB + ((size_t)(ks * 4) * 64 + lane) * 8;
#pragma unroll
        for (int cf = 0; cf < 4; ++cf) {
            bf16x8 bf = *(const bf16x8*)(bp + (size_t)cf * 512);
            acc[cf] = __builtin_amdgcn_mfma_f32_16x16x32_bf16(af, bf, acc[cf], 0, 0, 0);
        }
    }
#pragma unroll
    for (int cf = 0; cf < 4; ++cf)
#pragma unroll
        for (int j = 0; j < 4; ++j)
            C[(size_t)(rowBase + kg * 4 + j) * NCLS + cf * 16 + rl] = f2bf(acc[cf][j]);
}

// ---------------- agg1: h = relu(agg(xw1) + b1), one wave per node, bf16 in/out ----------------
__global__ __launch_bounds__(256) void agg1_kernel(const ushort* __restrict__ xw,
                                                   const int* __restrict__ rowptr,
                                                   const uint* __restrict__ csr,
                                                   const float* __restrict__ dinv,
                                                   const float* __restrict__ b1,
                                                   ushort* __restrict__ h) {
    int wid = (blockIdx.x * blockDim.x + threadIdx.x) >> 6;
    int lane = threadIdx.x & 63;
    if (wid >= NNODES) return;
    int beg = rowptr[wid], end = rowptr[wid + 1];
    float a0 = 0.f, a1 = 0.f, a2 = 0.f, a3 = 0.f;
    int j = beg;
    for (; j + 16 <= end; j += 16) {
        uint e[16];
#pragma unroll
        for (int q = 0; q < 16; ++q) e[q] = csr[j + q];
        uint v[16];
#pragma unroll
        for (int q = 0; q < 16; ++q)
            v[q] = *(const uint*)&xw[(size_t)(e[q] & 0xffffu) * NHID + lane * 2];
#pragma unroll
        for (int q = 0; q < 8; ++q) {
            float wq = h2f((ushort)(e[q] >> 16));
            a0 += wq * __uint_as_float(v[q] << 16);
            a1 += wq * __uint_as_float(v[q] & 0xffff0000u);
        }
#pragma unroll
        for (int q = 8; q < 16; ++q) {
            float wq = h2f((ushort)(e[q] >> 16));
            a2 += wq * __uint_as_float(v[q] << 16);
            a3 += wq * __uint_as_float(v[q] & 0xffff0000u);
        }
    }
    for (; j + 4 <= end; j += 4) {
        uint e[4];
#pragma unroll
        for (int q = 0; q < 4; ++q) e[q] = csr[j + q];
        uint v[4];
#pragma unroll
        for (int q = 0; q < 4; ++q)
            v[q] = *(const uint*)&xw[(size_t)(e[q] & 0xffffu) * NHID + lane * 2];
#pragma unroll
        for (int q = 0; q < 4; ++q) {
            float wq = h2f((ushort)(e[q] >> 16));
            a0 += wq * __uint_as_float(v[q] << 16);
            a1 += wq * __uint_as_float(v[q] & 0xffff0000u);
        }
    }
    for (; j < end; ++j) {
        uint e = csr[j];
        float wq = h2f((ushort)(e >> 16));
        uint v = *(const uint*)&xw[(size_t)(e & 0xffffu) * NHID + lane * 2];
        a0 += wq * __uint_as_float(v << 16);
        a1 += wq * __uint_as_float(v & 0xffff0000u);
    }
    a0 += a2; a1 += a3;
    float di = dinv[wid];
    float sl = di * di;
    uint xv = *(const uint*)&xw[(size_t)wid * NHID + lane * 2];
    float2 bv = *(const float2*)&b1[lane * 2];
    float r0 = di * a0 + sl * __uint_as_float(xv << 16) + bv.x;
    float r1 = di * a1 + sl * __uint_as_float(xv & 0xffff0000u) + bv.y;
    uint o = (uint)f2bf(fmaxf(r0, 0.f)) | ((uint)f2bf(fmaxf(r1, 0.f)) << 16);
    *(uint*)&h[(size_t)wid * NHID + lane * 2] = o;
}

// ---------------- agg2 + bias + log_softmax, one wave per node, bf16 in, f32 out ----------------
__global__ __launch_bounds__(256) void agg2_kernel(const ushort* __restrict__ xw,
                                                   const int* __restrict__ rowptr,
                                                   const uint* __restrict__ csr,
                                                   const float* __restrict__ dinv,
                                                   const float* __restrict__ b2,
                                                   float* __restrict__ out) {
    int wid = (blockIdx.x * blockDim.x + threadIdx.x) >> 6;
    int lane = threadIdx.x & 63;
    if (wid >= NNODES) return;
    int beg = rowptr[wid], end = rowptr[wid + 1];
    float a = 0.f, b = 0.f;
    int j = beg;
    for (; j + 16 <= end; j += 16) {
        uint e[16];
#pragma unroll
        for (int q = 0; q < 16; ++q) e[q] = csr[j + q];
        float v[16];
#pragma unroll
        for (int q = 0; q < 16; ++q)
            v[q] = bf2f(xw[(size_t)(e[q] & 0xffffu) * NCLS + lane]);
#pragma unroll
        for (int q = 0; q < 8; ++q) a += h2f((ushort)(e[q] >> 16)) * v[q];
#pragma unroll
        for (int q = 8; q < 16; ++q) b += h2f((ushort)(e[q] >> 16)) * v[q];
    }
    for (; j + 4 <= end; j += 4) {
        uint e[4];
#pragma unroll
        for (int q = 0; q < 4; ++q) e[q] = csr[j + q];
        float v[4];
#pragma unroll
        for (int q = 0; q < 4; ++q)
            v[q] = bf2f(xw[(size_t)(e[q] & 0xffffu) * NCLS + lane]);
#pragma unroll
        for (int q = 0; q < 4; ++q) a += h2f((ushort)(e[q] >> 16)) * v[q];
    }
    for (; j < end; ++j) {
        uint e = csr[j];
        a += h2f((ushort)(e >> 16)) * bf2f(xw[(size_t)(e & 0xffffu) * NCLS + lane]);
    }
    a += b;
    float di = dinv[wid];
    float o = di * a + di * di * bf2f(xw[(size_t)wid * NCLS + lane]) + b2[lane];
    float m = o;
#pragma unroll
    for (int off = 32; off; off >>= 1) m = fmaxf(m, __shfl_xor(m, off, 64));
    float ex = __expf(o - m);
    float ssum = ex;
#pragma unroll
    for (int off = 32; off; off >>= 1) ssum += __shfl_xor(ssum, off, 64);
    out[(size_t)wid * NCLS + lane] = (o - m) - __logf(ssum);
}

// ---------------- launch ----------------

extern "C" void kernel_launch(void* const* d_in, const int* in_sizes, int n_in,
                              void* d_out, int out_size, void* d_ws, size_t ws_size,
                              hipStream_t stream) {
    const float* x  = (const float*)d_in[0];
    const int*   ei = (const int*)d_in[1];
    const int*   src = ei;
    const int*   dst = ei + NEDGES;
    const float* W1 = (const float*)d_in[2];
    const float* b1 = (const float*)d_in[3];
    const float* W2 = (const float*)d_in[4];
    const float* b2 = (const float*)d_in[5];
    float* out = (float*)d_out;

    char* w = (char*)d_ws;
    auto alloc = [&](size_t bytes) {
        char* p = w;
        w += (bytes + 255) & ~(size_t)255;
        return p;
    };
    int*    deg    = (int*)alloc(NNODES * 4);
    int*    cursor = (int*)alloc(NNODES * 4);
    int*    rowptr = (int*)alloc((NNODES + 1) * 4);
    int*    blkSum = (int*)alloc(SCAN_NB * 4);
    uint*   csr    = (uint*)alloc((size_t)NEDGES * 4);
    float*  dinv   = (float*)alloc(NNODES * 4);
    ushort* pack1  = (ushort*)alloc((size_t)16 * 8 * 64 * 8 * 2);
    ushort* pack2  = (ushort*)alloc((size_t)4 * 4 * 64 * 8 * 2);
    ushort* xw1    = (ushort*)alloc((size_t)NNODES * NHID * 2);
    ushort* h      = (ushort*)alloc((size_t)NNODES * NHID * 2);
    ushort* xw2    = (ushort*)alloc((size_t)NNODES * NCLS * 2);

    const int n4 = (NNODES + 3) / 4;  // deg only (cursor written by scan3)
    clear_kernel<<<(n4 + 255) / 256, 256, 0, stream>>>((int4*)deg, n4);

    deg_kernel<<<(NEDGES / 4 + 255) / 256, 256, 0, stream>>>((const int4*)dst, deg);
    scan1_kernel<<<SCAN_NB, SCAN_BLK, 0, stream>>>(deg, blkSum, dinv);
    scan3_kernel<<<SCAN_NB, SCAN_BLK, 0, stream>>>(deg, blkSum, rowptr, cursor);
    scatter_kernel<<<(NEDGES + 255) / 256, 256, 0, stream>>>(src, dst, cursor, dinv, csr);

    pack_kernel<<<(16 * 8 * 64 * 8 + 4 * 4 * 64 * 8 + 255) / 256, 256, 0, stream>>>(W1, W2, pack1, pack2);

    // layer 1 (B-in-regs, depth-2 reg-staged bf16 LDS pipeline)
    gemm1_kernel<<<(NNODES + 63) / 64, 256, 0, stream>>>(x, pack1, xw1);
    agg1_kernel<<<(NNODES * 64 + 255) / 256, 256, 0, stream>>>(xw1, rowptr, csr, dinv, b1, h);

    // layer 2 (+ fused bias + log_softmax)
    gemm2_kernel<<<(NNODES / 16 + 3) / 4, 256, 0, stream>>>(h, pack2, xw2);
    agg2_kernel<<<(NNODES * 64 + 255) / 256, 256, 0, stream>>>(xw2, rowptr, csr, dinv, b2, out);
}